// Round 1
// baseline (1191.591 us; speedup 1.0000x reference)
//
#include <hip/hip_runtime.h>
#include <math.h>

static constexpr int TNFEAT  = 128;
static constexpr int TNHEADS = 8;
static constexpr int C1      = 512;  // NHID*NHEADS
static constexpr int C2      = 64;   // NCLASS

__global__ void k_zero(int* __restrict__ p, int n) {
  int i = blockIdx.x * blockDim.x + threadIdx.x;
  if (i < n) p[i] = 0;
}

__global__ void k_hist(const int* __restrict__ src, int* __restrict__ deg, int E) {
  int i = blockIdx.x * blockDim.x + threadIdx.x;
  if (i < E) atomicAdd(&deg[src[i]], 1);
}

__global__ __launch_bounds__(1024) void k_scan(const int* __restrict__ deg,
                                               int* __restrict__ offs, int n) {
  __shared__ int sdata[1024];
  __shared__ int s_carry;
  int tid = threadIdx.x;
  if (tid == 0) s_carry = 0;
  __syncthreads();
  for (int base = 0; base < n; base += 1024) {
    int i = base + tid;
    int v = (i < n) ? deg[i] : 0;
    sdata[tid] = v;
    __syncthreads();
    for (int ofs = 1; ofs < 1024; ofs <<= 1) {
      int t = (tid >= ofs) ? sdata[tid - ofs] : 0;
      __syncthreads();
      sdata[tid] += t;
      __syncthreads();
    }
    int inc = sdata[tid];
    int c = s_carry;
    __syncthreads();
    if (i < n) offs[i + 1] = c + inc;
    if (tid == 1023) s_carry = c + sdata[1023];
    __syncthreads();
  }
  if (tid == 0) offs[0] = 0;
}

__global__ void k_copy(const int* __restrict__ offs, int* __restrict__ cur, int n) {
  int i = blockIdx.x * blockDim.x + threadIdx.x;
  if (i < n) cur[i] = offs[i];
}

__global__ void k_fill(const int* __restrict__ src, const int* __restrict__ dst,
                       int* __restrict__ cur, int* __restrict__ adj, int E) {
  int i = blockIdx.x * blockDim.x + threadIdx.x;
  if (i < E) {
    int p = atomicAdd(&cur[src[i]], 1);
    adj[p] = dst[i];
  }
}

// C[m, c] = sum_k A[m,k] * W[head(c)][k][c%Fh],  W blocks [NHEADS][K][Fh]
template <int FH_SHIFT>
__global__ __launch_bounds__(256) void k_gemm(const float* __restrict__ A,
                                              const float* __restrict__ W,
                                              float* __restrict__ C,
                                              int M, int K, int Cout) {
  constexpr int Fh = 1 << FH_SHIFT;
  __shared__ float As[64][65];
  __shared__ float Ws[64][65];
  int row0 = blockIdx.x * 64, col0 = blockIdx.y * 64;
  int tid = threadIdx.x;
  int tx = tid & 15, ty = tid >> 4;
  float acc[4][4] = {};
  for (int k0 = 0; k0 < K; k0 += 64) {
    #pragma unroll
    for (int i = tid; i < 64 * 64; i += 256) {
      int r = i >> 6, c = i & 63;
      int gr = row0 + r;
      As[r][c] = (gr < M) ? A[(size_t)gr * K + k0 + c] : 0.f;
    }
    #pragma unroll
    for (int i = tid; i < 64 * 64; i += 256) {
      int r = i >> 6, c = i & 63;
      int gk = k0 + r, gc = col0 + c;
      int head = gc >> FH_SHIFT, j = gc & (Fh - 1);
      Ws[r][c] = W[((size_t)head * K + gk) * Fh + j];
    }
    __syncthreads();
    for (int kk = 0; kk < 64; ++kk) {
      float a0[4], b0[4];
      #pragma unroll
      for (int i = 0; i < 4; i++) a0[i] = As[ty * 4 + i][kk];
      #pragma unroll
      for (int j = 0; j < 4; j++) b0[j] = Ws[kk][tx * 4 + j];
      #pragma unroll
      for (int i = 0; i < 4; i++)
        #pragma unroll
        for (int j = 0; j < 4; j++)
          acc[i][j] = fmaf(a0[i], b0[j], acc[i][j]);
    }
    __syncthreads();
  }
  #pragma unroll
  for (int i = 0; i < 4; i++) {
    int gr = row0 + ty * 4 + i;
    if (gr < M) {
      #pragma unroll
      for (int j = 0; j < 4; j++)
        C[(size_t)gr * Cout + col0 + tx * 4 + j] = acc[i][j];
    }
  }
}

// per (node, head): s_src / s_dst dot products
template <int FH>
__global__ void k_scores(const float* __restrict__ H, const float* __restrict__ a,
                         float* __restrict__ ss, float* __restrict__ sd,
                         int n, int Cout) {
  int i = blockIdx.x * blockDim.x + threadIdx.x;
  if (i >= n * TNHEADS) return;
  int node = i >> 3, h = i & 7;
  const float4* hp = reinterpret_cast<const float4*>(H + (size_t)node * Cout + h * FH);
  const float4* as = reinterpret_cast<const float4*>(a + h * 2 * FH);
  const float4* ad = reinterpret_cast<const float4*>(a + h * 2 * FH + FH);
  float s0 = 0.f, s1v = 0.f;
  #pragma unroll
  for (int k = 0; k < FH / 4; ++k) {
    float4 hv = hp[k], av = as[k], dv = ad[k];
    s0  += hv.x * av.x + hv.y * av.y + hv.z * av.z + hv.w * av.w;
    s1v += hv.x * dv.x + hv.y * dv.y + hv.z * dv.z + hv.w * dv.w;
  }
  ss[i] = s0;
  sd[i] = s1v;
}

// one wave per (node, head); lane = feature (64). Layer-1 aggregation.
__global__ __launch_bounds__(256) void k_agg1(const float* __restrict__ H,
        const float* __restrict__ ss, const float* __restrict__ sd,
        const int* __restrict__ offs, const int* __restrict__ adj,
        float* __restrict__ outp, int n) {
  int wid = (blockIdx.x * 256 + threadIdx.x) >> 6;
  int lane = threadIdx.x & 63;
  int node = wid >> 3, h = wid & 7;
  if (node >= n) return;
  int beg = offs[node], end = offs[node + 1];
  float sS = ss[node * 8 + h];
  float acc = 0.f, rsum = 0.f;
  int d = (beg < end) ? adj[beg] : 0;
  for (int e = beg; e < end; ++e) {
    int dn = (e + 1 < end) ? adj[e + 1] : 0;
    float z = sS + sd[d * 8 + h];
    float lr = z > 0.f ? z : 0.2f * z;
    float w = __expf(-lr);
    acc = fmaf(w, H[(size_t)d * C1 + h * 64 + lane], acc);
    rsum += w;
    d = dn;
  }
  float v = acc / rsum;
  outp[(size_t)node * C1 + h * 64 + lane] = v > 0.f ? v : expm1f(v);
}

// one wave per node; lane = head*8 + feat. Layer-2 aggregation -> final out.
__global__ __launch_bounds__(256) void k_agg2(const float* __restrict__ H,
        const float* __restrict__ ss, const float* __restrict__ sd,
        const int* __restrict__ offs, const int* __restrict__ adj,
        float* __restrict__ outp, int n) {
  int wid = (blockIdx.x * 256 + threadIdx.x) >> 6;
  int lane = threadIdx.x & 63;
  int h = lane >> 3;
  if (wid >= n) return;
  int beg = offs[wid], end = offs[wid + 1];
  float sS = ss[wid * 8 + h];
  float acc = 0.f, rsum = 0.f;
  int d = (beg < end) ? adj[beg] : 0;
  for (int e = beg; e < end; ++e) {
    int dn = (e + 1 < end) ? adj[e + 1] : 0;
    float z = sS + sd[d * 8 + h];
    float lr = z > 0.f ? z : 0.2f * z;
    float w = __expf(-lr);
    acc = fmaf(w, H[(size_t)d * C2 + lane], acc);
    rsum += w;
    d = dn;
  }
  float v = acc / rsum;
  outp[(size_t)wid * C2 + lane] = v > 0.f ? v : expm1f(v);
}

extern "C" void kernel_launch(void* const* d_in, const int* in_sizes, int n_in,
                              void* d_out, int out_size, void* d_ws, size_t ws_size,
                              hipStream_t stream) {
  const float* x  = (const float*)d_in[0];
  const int*   ei = (const int*)d_in[1];
  const float* W1 = (const float*)d_in[2];
  const float* a1 = (const float*)d_in[3];
  const float* W2 = (const float*)d_in[4];
  const float* a2 = (const float*)d_in[5];
  float* out = (float*)d_out;

  int N = in_sizes[0] / TNFEAT;   // 50000
  int E = in_sizes[1] / 2;        // 850000
  const int* src = ei;
  const int* dst = ei + E;

  float* ws    = (float*)d_ws;
  float* h_all = ws;                                 // N*512
  float* h1    = h_all + (size_t)N * C1;             // N*512
  float* h2p   = h1 + (size_t)N * C1;                // N*64
  float* s1s   = h2p + (size_t)N * C2;               // N*8
  float* s1d   = s1s + (size_t)N * TNHEADS;
  float* s2s   = s1d + (size_t)N * TNHEADS;
  float* s2d   = s2s + (size_t)N * TNHEADS;
  int*   deg   = (int*)(s2d + (size_t)N * TNHEADS);  // N
  int*   offs  = deg + N;                            // N+1
  int*   cur   = offs + N + 1;                       // N
  int*   adj   = cur + N;                            // E

  // CSR build (by src)
  hipLaunchKernelGGL(k_zero, dim3((N + 255) / 256), dim3(256), 0, stream, deg, N);
  hipLaunchKernelGGL(k_hist, dim3((E + 255) / 256), dim3(256), 0, stream, src, deg, E);
  hipLaunchKernelGGL(k_scan, dim3(1), dim3(1024), 0, stream, deg, offs, N);
  hipLaunchKernelGGL(k_copy, dim3((N + 255) / 256), dim3(256), 0, stream, offs, cur, N);
  hipLaunchKernelGGL(k_fill, dim3((E + 255) / 256), dim3(256), 0, stream, src, dst, cur, adj, E);

  // Layer 1
  hipLaunchKernelGGL((k_gemm<6>), dim3((N + 63) / 64, C1 / 64), dim3(256), 0, stream,
                     x, W1, h_all, N, TNFEAT, C1);
  hipLaunchKernelGGL((k_scores<64>), dim3((N * 8 + 255) / 256), dim3(256), 0, stream,
                     h_all, a1, s1s, s1d, N, C1);
  hipLaunchKernelGGL(k_agg1, dim3(N * 2), dim3(256), 0, stream,
                     h_all, s1s, s1d, offs, adj, h1, N);

  // Layer 2
  hipLaunchKernelGGL((k_gemm<3>), dim3((N + 63) / 64, C2 / 64), dim3(256), 0, stream,
                     h1, W2, h2p, N, C1, C2);
  hipLaunchKernelGGL((k_scores<8>), dim3((N * 8 + 255) / 256), dim3(256), 0, stream,
                     h2p, a2, s2s, s2d, N, C2);
  hipLaunchKernelGGL(k_agg2, dim3(N / 4), dim3(256), 0, stream,
                     h2p, s2s, s2d, offs, adj, out, N);
}

// Round 2
// 833.186 us; speedup vs baseline: 1.4302x; 1.4302x over previous
//
#include <hip/hip_runtime.h>
#include <math.h>

static constexpr int TNFEAT  = 128;
static constexpr int TNHEADS = 8;
static constexpr int C1      = 512;  // NHID*NHEADS
static constexpr int C2      = 64;   // NCLASS

__global__ void k_zero(int* __restrict__ p, int n) {
  int i = blockIdx.x * blockDim.x + threadIdx.x;
  if (i < n) p[i] = 0;
}

__global__ void k_hist(const int* __restrict__ src, int* __restrict__ deg, int E) {
  int i = blockIdx.x * blockDim.x + threadIdx.x;
  if (i < E) atomicAdd(&deg[src[i]], 1);
}

__global__ __launch_bounds__(1024) void k_scan(const int* __restrict__ deg,
                                               int* __restrict__ offs, int n) {
  __shared__ int sdata[1024];
  __shared__ int s_carry;
  int tid = threadIdx.x;
  if (tid == 0) s_carry = 0;
  __syncthreads();
  for (int base = 0; base < n; base += 1024) {
    int i = base + tid;
    int v = (i < n) ? deg[i] : 0;
    sdata[tid] = v;
    __syncthreads();
    for (int ofs = 1; ofs < 1024; ofs <<= 1) {
      int t = (tid >= ofs) ? sdata[tid - ofs] : 0;
      __syncthreads();
      sdata[tid] += t;
      __syncthreads();
    }
    int inc = sdata[tid];
    int c = s_carry;
    __syncthreads();
    if (i < n) offs[i + 1] = c + inc;
    if (tid == 1023) s_carry = c + sdata[1023];
    __syncthreads();
  }
  if (tid == 0) offs[0] = 0;
}

__global__ void k_copy(const int* __restrict__ offs, int* __restrict__ cur, int n) {
  int i = blockIdx.x * blockDim.x + threadIdx.x;
  if (i < n) cur[i] = offs[i];
}

__global__ void k_fill(const int* __restrict__ src, const int* __restrict__ dst,
                       int* __restrict__ cur, int* __restrict__ adj, int E) {
  int i = blockIdx.x * blockDim.x + threadIdx.x;
  if (i < E) {
    int p = atomicAdd(&cur[src[i]], 1);
    adj[p] = dst[i];
  }
}

// C[m, c] = sum_k A[m,k] * W[head(c)][k][c%Fh],  W blocks [NHEADS][K][Fh]
template <int FH_SHIFT>
__global__ __launch_bounds__(256) void k_gemm(const float* __restrict__ A,
                                              const float* __restrict__ W,
                                              float* __restrict__ C,
                                              int M, int K, int Cout) {
  constexpr int Fh = 1 << FH_SHIFT;
  __shared__ float As[64][65];
  __shared__ float Ws[64][65];
  int row0 = blockIdx.x * 64, col0 = blockIdx.y * 64;
  int tid = threadIdx.x;
  int tx = tid & 15, ty = tid >> 4;
  float acc[4][4] = {};
  for (int k0 = 0; k0 < K; k0 += 64) {
    #pragma unroll
    for (int i = tid; i < 64 * 64; i += 256) {
      int r = i >> 6, c = i & 63;
      int gr = row0 + r;
      As[r][c] = (gr < M) ? A[(size_t)gr * K + k0 + c] : 0.f;
    }
    #pragma unroll
    for (int i = tid; i < 64 * 64; i += 256) {
      int r = i >> 6, c = i & 63;
      int gk = k0 + r, gc = col0 + c;
      int head = gc >> FH_SHIFT, j = gc & (Fh - 1);
      Ws[r][c] = W[((size_t)head * K + gk) * Fh + j];
    }
    __syncthreads();
    for (int kk = 0; kk < 64; ++kk) {
      float a0[4], b0[4];
      #pragma unroll
      for (int i = 0; i < 4; i++) a0[i] = As[ty * 4 + i][kk];
      #pragma unroll
      for (int j = 0; j < 4; j++) b0[j] = Ws[kk][tx * 4 + j];
      #pragma unroll
      for (int i = 0; i < 4; i++)
        #pragma unroll
        for (int j = 0; j < 4; j++)
          acc[i][j] = fmaf(a0[i], b0[j], acc[i][j]);
    }
    __syncthreads();
  }
  #pragma unroll
  for (int i = 0; i < 4; i++) {
    int gr = row0 + ty * 4 + i;
    if (gr < M) {
      #pragma unroll
      for (int j = 0; j < 4; j++)
        C[(size_t)gr * Cout + col0 + tx * 4 + j] = acc[i][j];
    }
  }
}

// per (node, head): s_src / s_dst dot products
template <int FH>
__global__ void k_scores(const float* __restrict__ H, const float* __restrict__ a,
                         float* __restrict__ ss, float* __restrict__ sd,
                         int n, int Cout) {
  int i = blockIdx.x * blockDim.x + threadIdx.x;
  if (i >= n * TNHEADS) return;
  int node = i >> 3, h = i & 7;
  const float4* hp = reinterpret_cast<const float4*>(H + (size_t)node * Cout + h * FH);
  const float4* as = reinterpret_cast<const float4*>(a + h * 2 * FH);
  const float4* ad = reinterpret_cast<const float4*>(a + h * 2 * FH + FH);
  float s0 = 0.f, s1v = 0.f;
  #pragma unroll
  for (int k = 0; k < FH / 4; ++k) {
    float4 hv = hp[k], av = as[k], dv = ad[k];
    s0  += hv.x * av.x + hv.y * av.y + hv.z * av.z + hv.w * av.w;
    s1v += hv.x * dv.x + hv.y * dv.y + hv.z * dv.z + hv.w * dv.w;
  }
  ss[i] = s0;
  sd[i] = s1v;
}

// Layer-1 aggregation: ONE wave per node, all 8 heads.
// lane covers features [lane*4 .. lane*4+3] (heads 0-3) and [256+lane*4 ...] (heads 4-7).
// Unrolled by 4 edges with shfl-broadcast adjacency for memory-level parallelism.
__global__ __launch_bounds__(256) void k_agg1(const float* __restrict__ H,
        const float* __restrict__ ss, const float* __restrict__ sd,
        const int* __restrict__ offs, const int* __restrict__ adj,
        float* __restrict__ outp, int n) {
  int node = (blockIdx.x * 256 + threadIdx.x) >> 6;
  int lane = threadIdx.x & 63;
  if (node >= n) return;
  int hlo = lane >> 4;        // head for low 256-feature half
  int hhi = 4 + hlo;          // head for high half
  int beg = offs[node], end = offs[node + 1];
  float ssLo = ss[node * 8 + hlo];
  float ssHi = ss[node * 8 + hhi];
  const float4* Hv = reinterpret_cast<const float4*>(H);
  float4 acc0 = {0.f, 0.f, 0.f, 0.f}, acc1 = {0.f, 0.f, 0.f, 0.f};
  float rs0 = 0.f, rs1 = 0.f;
  for (int e = beg; e < end; e += 4) {
    int m = end - e; if (m > 4) m = 4;
    int li = lane & 3; if (li >= m) li = m - 1;
    int dl = adj[e + li];
    int dr[4];
    #pragma unroll
    for (int i = 0; i < 4; i++) dr[i] = __shfl(dl, i);
    float sdl[4], sdh[4];
    float4 r0[4], r1[4];
    #pragma unroll
    for (int i = 0; i < 4; i++) {
      if (i < m) {
        sdl[i] = sd[dr[i] * 8 + hlo];
        sdh[i] = sd[dr[i] * 8 + hhi];
        r0[i] = Hv[(size_t)dr[i] * 128 + lane];
        r1[i] = Hv[(size_t)dr[i] * 128 + 64 + lane];
      }
    }
    #pragma unroll
    for (int i = 0; i < 4; i++) {
      if (i < m) {
        float zl = ssLo + sdl[i];
        float zh = ssHi + sdh[i];
        float wl = __expf(-(zl > 0.f ? zl : 0.2f * zl));
        float wh = __expf(-(zh > 0.f ? zh : 0.2f * zh));
        acc0.x = fmaf(wl, r0[i].x, acc0.x);
        acc0.y = fmaf(wl, r0[i].y, acc0.y);
        acc0.z = fmaf(wl, r0[i].z, acc0.z);
        acc0.w = fmaf(wl, r0[i].w, acc0.w);
        acc1.x = fmaf(wh, r1[i].x, acc1.x);
        acc1.y = fmaf(wh, r1[i].y, acc1.y);
        acc1.z = fmaf(wh, r1[i].z, acc1.z);
        acc1.w = fmaf(wh, r1[i].w, acc1.w);
        rs0 += wl;
        rs1 += wh;
      }
    }
  }
  float4 o0, o1;
  float inv0 = 1.f / rs0, inv1 = 1.f / rs1;
  o0.x = acc0.x * inv0; o0.y = acc0.y * inv0; o0.z = acc0.z * inv0; o0.w = acc0.w * inv0;
  o1.x = acc1.x * inv1; o1.y = acc1.y * inv1; o1.z = acc1.z * inv1; o1.w = acc1.w * inv1;
  o0.x = o0.x > 0.f ? o0.x : expm1f(o0.x);
  o0.y = o0.y > 0.f ? o0.y : expm1f(o0.y);
  o0.z = o0.z > 0.f ? o0.z : expm1f(o0.z);
  o0.w = o0.w > 0.f ? o0.w : expm1f(o0.w);
  o1.x = o1.x > 0.f ? o1.x : expm1f(o1.x);
  o1.y = o1.y > 0.f ? o1.y : expm1f(o1.y);
  o1.z = o1.z > 0.f ? o1.z : expm1f(o1.z);
  o1.w = o1.w > 0.f ? o1.w : expm1f(o1.w);
  float4* Ov = reinterpret_cast<float4*>(outp);
  Ov[(size_t)node * 128 + lane] = o0;
  Ov[(size_t)node * 128 + 64 + lane] = o1;
}

// Layer-2 aggregation: one wave per node; lane = head*8 + feat. Unroll 4.
__global__ __launch_bounds__(256) void k_agg2(const float* __restrict__ H,
        const float* __restrict__ ss, const float* __restrict__ sd,
        const int* __restrict__ offs, const int* __restrict__ adj,
        float* __restrict__ outp, int n) {
  int node = (blockIdx.x * 256 + threadIdx.x) >> 6;
  int lane = threadIdx.x & 63;
  int h = lane >> 3;
  if (node >= n) return;
  int beg = offs[node], end = offs[node + 1];
  float sS = ss[node * 8 + h];
  float acc = 0.f, rsum = 0.f;
  for (int e = beg; e < end; e += 4) {
    int m = end - e; if (m > 4) m = 4;
    int li = lane & 3; if (li >= m) li = m - 1;
    int dl = adj[e + li];
    int dr[4];
    #pragma unroll
    for (int i = 0; i < 4; i++) dr[i] = __shfl(dl, i);
    float sdv[4], rv[4];
    #pragma unroll
    for (int i = 0; i < 4; i++) {
      if (i < m) {
        sdv[i] = sd[dr[i] * 8 + h];
        rv[i] = H[(size_t)dr[i] * 64 + lane];
      }
    }
    #pragma unroll
    for (int i = 0; i < 4; i++) {
      if (i < m) {
        float z = sS + sdv[i];
        float w = __expf(-(z > 0.f ? z : 0.2f * z));
        acc = fmaf(w, rv[i], acc);
        rsum += w;
      }
    }
  }
  float v = acc / rsum;
  outp[(size_t)node * 64 + lane] = v > 0.f ? v : expm1f(v);
}

extern "C" void kernel_launch(void* const* d_in, const int* in_sizes, int n_in,
                              void* d_out, int out_size, void* d_ws, size_t ws_size,
                              hipStream_t stream) {
  const float* x  = (const float*)d_in[0];
  const int*   ei = (const int*)d_in[1];
  const float* W1 = (const float*)d_in[2];
  const float* a1 = (const float*)d_in[3];
  const float* W2 = (const float*)d_in[4];
  const float* a2 = (const float*)d_in[5];
  float* out = (float*)d_out;

  int N = in_sizes[0] / TNFEAT;   // 50000
  int E = in_sizes[1] / 2;        // 850000
  const int* src = ei;
  const int* dst = ei + E;

  float* ws    = (float*)d_ws;
  float* h_all = ws;                                 // N*512
  float* h1    = h_all + (size_t)N * C1;             // N*512
  float* h2p   = h1 + (size_t)N * C1;                // N*64
  float* s1s   = h2p + (size_t)N * C2;               // N*8
  float* s1d   = s1s + (size_t)N * TNHEADS;
  float* s2s   = s1d + (size_t)N * TNHEADS;
  float* s2d   = s2s + (size_t)N * TNHEADS;
  int*   deg   = (int*)(s2d + (size_t)N * TNHEADS);  // N
  int*   offs  = deg + N;                            // N+1
  int*   cur   = offs + N + 1;                       // N
  int*   adj   = cur + N;                            // E

  // CSR build (by src)
  hipLaunchKernelGGL(k_zero, dim3((N + 255) / 256), dim3(256), 0, stream, deg, N);
  hipLaunchKernelGGL(k_hist, dim3((E + 255) / 256), dim3(256), 0, stream, src, deg, E);
  hipLaunchKernelGGL(k_scan, dim3(1), dim3(1024), 0, stream, deg, offs, N);
  hipLaunchKernelGGL(k_copy, dim3((N + 255) / 256), dim3(256), 0, stream, offs, cur, N);
  hipLaunchKernelGGL(k_fill, dim3((E + 255) / 256), dim3(256), 0, stream, src, dst, cur, adj, E);

  // Layer 1
  hipLaunchKernelGGL((k_gemm<6>), dim3((N + 63) / 64, C1 / 64), dim3(256), 0, stream,
                     x, W1, h_all, N, TNFEAT, C1);
  hipLaunchKernelGGL((k_scores<64>), dim3((N * 8 + 255) / 256), dim3(256), 0, stream,
                     h_all, a1, s1s, s1d, N, C1);
  hipLaunchKernelGGL(k_agg1, dim3((N + 3) / 4), dim3(256), 0, stream,
                     h_all, s1s, s1d, offs, adj, h1, N);

  // Layer 2
  hipLaunchKernelGGL((k_gemm<3>), dim3((N + 63) / 64, C2 / 64), dim3(256), 0, stream,
                     h1, W2, h2p, N, C1, C2);
  hipLaunchKernelGGL((k_scores<8>), dim3((N * 8 + 255) / 256), dim3(256), 0, stream,
                     h2p, a2, s2s, s2d, N, C2);
  hipLaunchKernelGGL(k_agg2, dim3((N + 3) / 4), dim3(256), 0, stream,
                     h2p, s2s, s2d, offs, adj, out, N);
}

// Round 3
// 599.612 us; speedup vs baseline: 1.9873x; 1.3895x over previous
//
#include <hip/hip_runtime.h>
#include <math.h>

typedef unsigned int u32;
typedef unsigned short u16;

static constexpr int TNFEAT  = 128;
static constexpr int TNHEADS = 8;
static constexpr int C1      = 512;  // NHID*NHEADS
static constexpr int C2      = 64;   // NCLASS

__device__ inline float bf2f(u16 u) {
  union { u32 i; float f; } c; c.i = ((u32)u) << 16; return c.f;
}
__device__ inline u16 f2bf(float f) {
  union { float f; u32 i; } c; c.f = f;
  u32 r = c.i + 0x7FFF + ((c.i >> 16) & 1);   // round-nearest-even
  return (u16)(r >> 16);
}

__global__ void k_zero(int* __restrict__ p, int n) {
  int i = blockIdx.x * blockDim.x + threadIdx.x;
  if (i < n) p[i] = 0;
}

__global__ void k_hist(const int* __restrict__ src, int* __restrict__ deg, int E) {
  int i = blockIdx.x * blockDim.x + threadIdx.x;
  if (i < E) atomicAdd(&deg[src[i]], 1);
}

// pass 1: per-block (1024) inclusive scan -> loc, block totals -> bsum
__global__ __launch_bounds__(1024) void k_bscan1(const int* __restrict__ deg,
                                                 int* __restrict__ loc,
                                                 int* __restrict__ bsum, int n) {
  __shared__ int sdata[1024];
  int t = threadIdx.x;
  int i = blockIdx.x * 1024 + t;
  int v = (i < n) ? deg[i] : 0;
  sdata[t] = v;
  __syncthreads();
  for (int ofs = 1; ofs < 1024; ofs <<= 1) {
    int tv = (t >= ofs) ? sdata[t - ofs] : 0;
    __syncthreads();
    sdata[t] += tv;
    __syncthreads();
  }
  if (i < n) loc[i] = sdata[t];
  if (t == 1023) bsum[blockIdx.x] = sdata[1023];
}

// pass 2: single wave scans the (<=64) block sums in place (inclusive)
__global__ void k_bscan2(int* __restrict__ bsum, int nb) {
  int t = threadIdx.x;
  int v = (t < nb) ? bsum[t] : 0;
  #pragma unroll
  for (int ofs = 1; ofs < 64; ofs <<= 1) {
    int u = __shfl_up(v, ofs);
    if (t >= ofs) v += u;
  }
  if (t < nb) bsum[t] = v;
}

// pass 3: offs[i+1] = loc[i] + prefix(block)
__global__ __launch_bounds__(1024) void k_offs(const int* __restrict__ loc,
                                               const int* __restrict__ bsum,
                                               int* __restrict__ offs, int n) {
  int b = blockIdx.x;
  int i = b * 1024 + threadIdx.x;
  int base = (b > 0) ? bsum[b - 1] : 0;
  if (i < n) offs[i + 1] = base + loc[i];
  if (i == 0) offs[0] = 0;
}

__global__ void k_copy(const int* __restrict__ offs, int* __restrict__ cur, int n) {
  int i = blockIdx.x * blockDim.x + threadIdx.x;
  if (i < n) cur[i] = offs[i];
}

__global__ void k_fill(const int* __restrict__ src, const int* __restrict__ dst,
                       int* __restrict__ cur, int* __restrict__ adj, int E) {
  int i = blockIdx.x * blockDim.x + threadIdx.x;
  if (i < E) {
    int p = atomicAdd(&cur[src[i]], 1);
    adj[p] = dst[i];
  }
}

// C[m, c] = sum_k A[m,k] * W[head(c)][k][c%Fh]; output stored bf16.
template <int FH_SHIFT>
__global__ __launch_bounds__(256) void k_gemm(const float* __restrict__ A,
                                              const float* __restrict__ W,
                                              u16* __restrict__ C,
                                              int M, int K, int Cout) {
  constexpr int Fh = 1 << FH_SHIFT;
  __shared__ float As[64][65];
  __shared__ float Ws[64][65];
  int row0 = blockIdx.x * 64, col0 = blockIdx.y * 64;
  int tid = threadIdx.x;
  int tx = tid & 15, ty = tid >> 4;
  float acc[4][4] = {};
  for (int k0 = 0; k0 < K; k0 += 64) {
    #pragma unroll
    for (int i = tid; i < 64 * 64; i += 256) {
      int r = i >> 6, c = i & 63;
      int gr = row0 + r;
      As[r][c] = (gr < M) ? A[(size_t)gr * K + k0 + c] : 0.f;
    }
    #pragma unroll
    for (int i = tid; i < 64 * 64; i += 256) {
      int r = i >> 6, c = i & 63;
      int gk = k0 + r, gc = col0 + c;
      int head = gc >> FH_SHIFT, j = gc & (Fh - 1);
      Ws[r][c] = W[((size_t)head * K + gk) * Fh + j];
    }
    __syncthreads();
    for (int kk = 0; kk < 64; ++kk) {
      float a0[4], b0[4];
      #pragma unroll
      for (int i = 0; i < 4; i++) a0[i] = As[ty * 4 + i][kk];
      #pragma unroll
      for (int j = 0; j < 4; j++) b0[j] = Ws[kk][tx * 4 + j];
      #pragma unroll
      for (int i = 0; i < 4; i++)
        #pragma unroll
        for (int j = 0; j < 4; j++)
          acc[i][j] = fmaf(a0[i], b0[j], acc[i][j]);
    }
    __syncthreads();
  }
  #pragma unroll
  for (int i = 0; i < 4; i++) {
    int gr = row0 + ty * 4 + i;
    if (gr < M) {
      ushort4 pk;
      pk.x = f2bf(acc[i][0]); pk.y = f2bf(acc[i][1]);
      pk.z = f2bf(acc[i][2]); pk.w = f2bf(acc[i][3]);
      *reinterpret_cast<ushort4*>(&C[(size_t)gr * Cout + col0 + tx * 4]) = pk;
    }
  }
}

// per (node, head): s_src / s_dst dot products from bf16 H
template <int FH>
__global__ void k_scores(const u16* __restrict__ H, const float* __restrict__ a,
                         float* __restrict__ ss, float* __restrict__ sd,
                         int n, int Cout) {
  int i = blockIdx.x * blockDim.x + threadIdx.x;
  if (i >= n * TNHEADS) return;
  int node = i >> 3, h = i & 7;
  const uint4* hp = reinterpret_cast<const uint4*>(H + (size_t)node * Cout + h * FH);
  const float* as = a + h * 2 * FH;
  float s0 = 0.f, s1v = 0.f;
  #pragma unroll
  for (int k = 0; k < FH / 8; ++k) {
    uint4 v = hp[k];
    u32 wv[4] = {v.x, v.y, v.z, v.w};
    #pragma unroll
    for (int q = 0; q < 4; q++) {
      float lo = bf2f((u16)(wv[q] & 0xffff));
      float hi = bf2f((u16)(wv[q] >> 16));
      int base = k * 8 + q * 2;
      s0  += lo * as[base]      + hi * as[base + 1];
      s1v += lo * as[FH + base] + hi * as[FH + base + 1];
    }
  }
  ss[i] = s0;
  sd[i] = s1v;
}

// Layer-1 aggregation: one wave per node; lane covers 8 bf16 feats (head = lane>>3).
// Unroll 8 edges; one uint4 row-load + one score load per lane per edge.
__global__ __launch_bounds__(256) void k_agg1(const u16* __restrict__ H,
        const float* __restrict__ ss, const float* __restrict__ sd,
        const int* __restrict__ offs, const int* __restrict__ adj,
        float* __restrict__ outp, int n) {
  int node = (blockIdx.x * 256 + threadIdx.x) >> 6;
  int lane = threadIdx.x & 63;
  if (node >= n) return;
  int head = lane >> 3;
  int beg = offs[node], end = offs[node + 1];
  float sS = ss[node * 8 + head];
  const uint4* Hv = reinterpret_cast<const uint4*>(H);  // 64 uint4 per row
  float acc[8] = {};
  float rsum = 0.f;
  for (int e = beg; e < end; e += 8) {
    int m = end - e; if (m > 8) m = 8;
    int li = lane & 7; if (li >= m) li = m - 1;
    int dl = adj[e + li];
    int dr[8];
    #pragma unroll
    for (int i = 0; i < 8; i++) dr[i] = __shfl(dl, i);
    float sdv[8];
    uint4 rv[8];
    #pragma unroll
    for (int i = 0; i < 8; i++) {
      if (i < m) {
        sdv[i] = sd[dr[i] * 8 + head];
        rv[i] = Hv[(size_t)dr[i] * 64 + lane];
      }
    }
    #pragma unroll
    for (int i = 0; i < 8; i++) {
      if (i < m) {
        float z = sS + sdv[i];
        float w = __expf(-(z > 0.f ? z : 0.2f * z));
        rsum += w;
        u32 w0 = rv[i].x, w1 = rv[i].y, w2 = rv[i].z, w3 = rv[i].w;
        acc[0] = fmaf(w, bf2f((u16)(w0 & 0xffff)), acc[0]);
        acc[1] = fmaf(w, bf2f((u16)(w0 >> 16)),    acc[1]);
        acc[2] = fmaf(w, bf2f((u16)(w1 & 0xffff)), acc[2]);
        acc[3] = fmaf(w, bf2f((u16)(w1 >> 16)),    acc[3]);
        acc[4] = fmaf(w, bf2f((u16)(w2 & 0xffff)), acc[4]);
        acc[5] = fmaf(w, bf2f((u16)(w2 >> 16)),    acc[5]);
        acc[6] = fmaf(w, bf2f((u16)(w3 & 0xffff)), acc[6]);
        acc[7] = fmaf(w, bf2f((u16)(w3 >> 16)),    acc[7]);
      }
    }
  }
  float inv = 1.f / rsum;
  float o[8];
  #pragma unroll
  for (int k = 0; k < 8; k++) {
    float v = acc[k] * inv;
    o[k] = v > 0.f ? v : expm1f(v);
  }
  float4* Ov = reinterpret_cast<float4*>(outp);
  Ov[(size_t)node * 128 + lane * 2]     = make_float4(o[0], o[1], o[2], o[3]);
  Ov[(size_t)node * 128 + lane * 2 + 1] = make_float4(o[4], o[5], o[6], o[7]);
}

// Layer-2 aggregation: one wave per node; 8 edges per iter.
// lane = li*8+fg: edge-slot li = lane>>3, feature-group fg = lane&7 (== head).
// Cross-lane reduce over li at the end.
__global__ __launch_bounds__(256) void k_agg2(const u16* __restrict__ H,
        const float* __restrict__ ss, const float* __restrict__ sd,
        const int* __restrict__ offs, const int* __restrict__ adj,
        float* __restrict__ outp, int n) {
  int node = (blockIdx.x * 256 + threadIdx.x) >> 6;
  int lane = threadIdx.x & 63;
  if (node >= n) return;
  int li = lane >> 3, fg = lane & 7;
  int beg = offs[node], end = offs[node + 1];
  float sS = ss[node * 8 + fg];
  const uint4* Hv = reinterpret_cast<const uint4*>(H);  // 8 uint4 per row
  float acc[8] = {};
  float rsum = 0.f;
  for (int e = beg; e < end; e += 8) {
    int m = end - e; if (m > 8) m = 8;
    int ll = lane & 7; if (ll >= m) ll = m - 1;
    int dl = adj[e + ll];
    int d = __shfl(dl, li);
    if (li < m) {
      float sdv = sd[d * 8 + fg];
      uint4 rv = Hv[(size_t)d * 8 + fg];
      float z = sS + sdv;
      float w = __expf(-(z > 0.f ? z : 0.2f * z));
      rsum += w;
      u32 w0 = rv.x, w1 = rv.y, w2 = rv.z, w3 = rv.w;
      acc[0] = fmaf(w, bf2f((u16)(w0 & 0xffff)), acc[0]);
      acc[1] = fmaf(w, bf2f((u16)(w0 >> 16)),    acc[1]);
      acc[2] = fmaf(w, bf2f((u16)(w1 & 0xffff)), acc[2]);
      acc[3] = fmaf(w, bf2f((u16)(w1 >> 16)),    acc[3]);
      acc[4] = fmaf(w, bf2f((u16)(w2 & 0xffff)), acc[4]);
      acc[5] = fmaf(w, bf2f((u16)(w2 >> 16)),    acc[5]);
      acc[6] = fmaf(w, bf2f((u16)(w3 & 0xffff)), acc[6]);
      acc[7] = fmaf(w, bf2f((u16)(w3 >> 16)),    acc[7]);
    }
  }
  #pragma unroll
  for (int mask = 8; mask < 64; mask <<= 1) {
    rsum += __shfl_xor(rsum, mask);
    #pragma unroll
    for (int k = 0; k < 8; k++) acc[k] += __shfl_xor(acc[k], mask);
  }
  if (li == 0) {
    float inv = 1.f / rsum;
    float o[8];
    #pragma unroll
    for (int k = 0; k < 8; k++) {
      float v = acc[k] * inv;
      o[k] = v > 0.f ? v : expm1f(v);
    }
    float4* Ov = reinterpret_cast<float4*>(outp);
    Ov[(size_t)node * 16 + fg * 2]     = make_float4(o[0], o[1], o[2], o[3]);
    Ov[(size_t)node * 16 + fg * 2 + 1] = make_float4(o[4], o[5], o[6], o[7]);
  }
}

extern "C" void kernel_launch(void* const* d_in, const int* in_sizes, int n_in,
                              void* d_out, int out_size, void* d_ws, size_t ws_size,
                              hipStream_t stream) {
  const float* x  = (const float*)d_in[0];
  const int*   ei = (const int*)d_in[1];
  const float* W1 = (const float*)d_in[2];
  const float* a1 = (const float*)d_in[3];
  const float* W2 = (const float*)d_in[4];
  const float* a2 = (const float*)d_in[5];
  float* out = (float*)d_out;

  int N = in_sizes[0] / TNFEAT;   // 50000
  int E = in_sizes[1] / 2;        // 850000
  const int* src = ei;
  const int* dst = ei + E;
  int NB = (N + 1023) / 1024;     // 49 blocks for scan

  char* base = (char*)d_ws;
  size_t off = 0;
  auto take = [&](size_t bytes) { char* p = base + off; off = (off + bytes + 255) & ~(size_t)255; return p; };
  u16*   h_all = (u16*)take((size_t)N * C1 * 2);
  float* h1    = (float*)take((size_t)N * C1 * 4);
  u16*   h2p   = (u16*)take((size_t)N * C2 * 2);
  float* s1s   = (float*)take((size_t)N * 8 * 4);
  float* s1d   = (float*)take((size_t)N * 8 * 4);
  float* s2s   = (float*)take((size_t)N * 8 * 4);
  float* s2d   = (float*)take((size_t)N * 8 * 4);
  int*   deg   = (int*)take((size_t)N * 4);
  int*   offs  = (int*)take((size_t)(N + 1) * 4);
  int*   cur   = (int*)take((size_t)N * 4);
  int*   loc   = (int*)take((size_t)N * 4);
  int*   bsum  = (int*)take(64 * 4);
  int*   adj   = (int*)take((size_t)E * 4);

  // CSR build (by src)
  hipLaunchKernelGGL(k_zero, dim3((N + 255) / 256), dim3(256), 0, stream, deg, N);
  hipLaunchKernelGGL(k_hist, dim3((E + 255) / 256), dim3(256), 0, stream, src, deg, E);
  hipLaunchKernelGGL(k_bscan1, dim3(NB), dim3(1024), 0, stream, deg, loc, bsum, N);
  hipLaunchKernelGGL(k_bscan2, dim3(1), dim3(64), 0, stream, bsum, NB);
  hipLaunchKernelGGL(k_offs, dim3(NB), dim3(1024), 0, stream, loc, bsum, offs, N);
  hipLaunchKernelGGL(k_copy, dim3((N + 255) / 256), dim3(256), 0, stream, offs, cur, N);
  hipLaunchKernelGGL(k_fill, dim3((E + 255) / 256), dim3(256), 0, stream, src, dst, cur, adj, E);

  // Layer 1
  hipLaunchKernelGGL((k_gemm<6>), dim3((N + 63) / 64, C1 / 64), dim3(256), 0, stream,
                     x, W1, h_all, N, TNFEAT, C1);
  hipLaunchKernelGGL((k_scores<64>), dim3((N * 8 + 255) / 256), dim3(256), 0, stream,
                     h_all, a1, s1s, s1d, N, C1);
  hipLaunchKernelGGL(k_agg1, dim3((N + 3) / 4), dim3(256), 0, stream,
                     h_all, s1s, s1d, offs, adj, h1, N);

  // Layer 2
  hipLaunchKernelGGL((k_gemm<3>), dim3((N + 63) / 64, C2 / 64), dim3(256), 0, stream,
                     h1, W2, h2p, N, C1, C2);
  hipLaunchKernelGGL((k_scores<8>), dim3((N * 8 + 255) / 256), dim3(256), 0, stream,
                     h2p, a2, s2s, s2d, N, C2);
  hipLaunchKernelGGL(k_agg2, dim3((N + 3) / 4), dim3(256), 0, stream,
                     h2p, s2s, s2d, offs, adj, out, N);
}

// Round 4
// 420.441 us; speedup vs baseline: 2.8341x; 1.4261x over previous
//
#include <hip/hip_runtime.h>
#include <math.h>

typedef unsigned int u32;
typedef unsigned short u16;
typedef __attribute__((ext_vector_type(8))) short bf16x8;
typedef __attribute__((ext_vector_type(4))) float f32x4;

static constexpr int TNFEAT  = 128;
static constexpr int TNHEADS = 8;
static constexpr int C1      = 512;  // NHID*NHEADS
static constexpr int C2      = 64;   // NCLASS

__device__ inline float bf2f(u16 u) {
  union { u32 i; float f; } c; c.i = ((u32)u) << 16; return c.f;
}
__device__ inline u16 f2bf(float f) {
  union { float f; u32 i; } c; c.f = f;
  u32 r = c.i + 0x7FFF + ((c.i >> 16) & 1);   // round-nearest-even
  return (u16)(r >> 16);
}

__global__ void k_zero(int* __restrict__ p, int n) {
  int i = blockIdx.x * blockDim.x + threadIdx.x;
  if (i < n) p[i] = 0;
}

__global__ void k_hist(const int* __restrict__ src, int* __restrict__ deg, int E) {
  int i = blockIdx.x * blockDim.x + threadIdx.x;
  if (i < E) atomicAdd(&deg[src[i]], 1);
}

__global__ __launch_bounds__(1024) void k_bscan1(const int* __restrict__ deg,
                                                 int* __restrict__ loc,
                                                 int* __restrict__ bsum, int n) {
  __shared__ int sdata[1024];
  int t = threadIdx.x;
  int i = blockIdx.x * 1024 + t;
  int v = (i < n) ? deg[i] : 0;
  sdata[t] = v;
  __syncthreads();
  for (int ofs = 1; ofs < 1024; ofs <<= 1) {
    int tv = (t >= ofs) ? sdata[t - ofs] : 0;
    __syncthreads();
    sdata[t] += tv;
    __syncthreads();
  }
  if (i < n) loc[i] = sdata[t];
  if (t == 1023) bsum[blockIdx.x] = sdata[1023];
}

__global__ void k_bscan2(int* __restrict__ bsum, int nb) {
  int t = threadIdx.x;
  int v = (t < nb) ? bsum[t] : 0;
  #pragma unroll
  for (int ofs = 1; ofs < 64; ofs <<= 1) {
    int u = __shfl_up(v, ofs);
    if (t >= ofs) v += u;
  }
  if (t < nb) bsum[t] = v;
}

__global__ __launch_bounds__(1024) void k_offs(const int* __restrict__ loc,
                                               const int* __restrict__ bsum,
                                               int* __restrict__ offs, int n) {
  int b = blockIdx.x;
  int i = b * 1024 + threadIdx.x;
  int base = (b > 0) ? bsum[b - 1] : 0;
  if (i < n) offs[i + 1] = base + loc[i];
  if (i == 0) offs[0] = 0;
}

__global__ void k_copy(const int* __restrict__ offs, int* __restrict__ cur, int n) {
  int i = blockIdx.x * blockDim.x + threadIdx.x;
  if (i < n) cur[i] = offs[i];
}

__global__ void k_fill(const int* __restrict__ src, const int* __restrict__ dst,
                       int* __restrict__ cur, int* __restrict__ adj, int E) {
  int i = blockIdx.x * blockDim.x + threadIdx.x;
  if (i < E) {
    int p = atomicAdd(&cur[src[i]], 1);
    adj[p] = dst[i];
  }
}

// fp32 -> (bf16 hi, bf16 lo), 4 elems/thread
__global__ void k_split(const float* __restrict__ in, u16* __restrict__ hi,
                        u16* __restrict__ lo, int n4) {
  int i = blockIdx.x * blockDim.x + threadIdx.x;
  if (i >= n4) return;
  float4 v = reinterpret_cast<const float4*>(in)[i];
  float f[4] = {v.x, v.y, v.z, v.w};
  ushort4 h, l;
  u16* hp = &h.x; u16* lp = &l.x;
  #pragma unroll
  for (int k = 0; k < 4; k++) {
    u16 hb = f2bf(f[k]);
    hp[k] = hb;
    lp[k] = f2bf(f[k] - bf2f(hb));
  }
  reinterpret_cast<ushort4*>(hi)[i] = h;
  reinterpret_cast<ushort4*>(lo)[i] = l;
}

// Pack W1 [8][128][64] into MFMA b-frag order:
// idx = ((cg*4 + ks)*64 + lane)*8 + j ; value = B1[ks*32+(lane>>4)*8+j][cg*16+(lane&15)]
// with B1[k][col] = W1[col>>6][k][col&63]
__global__ void k_packW1(const float* __restrict__ W1, u16* __restrict__ hi,
                         u16* __restrict__ lo) {
  int idx = blockIdx.x * 256 + threadIdx.x;
  if (idx >= 32 * 4 * 64 * 8) return;
  int j = idx & 7, lane = (idx >> 3) & 63, ks = (idx >> 9) & 3, cg = idx >> 11;
  int col = cg * 16 + (lane & 15);
  int k = ks * 32 + (lane >> 4) * 8 + j;
  float f = W1[((size_t)(col >> 6) * 128 + k) * 64 + (col & 63)];
  u16 h = f2bf(f);
  hi[idx] = h;
  lo[idx] = f2bf(f - bf2f(h));
}

// Pack W2 [8][512][8]: idx = ((cg*16 + ks)*64 + lane)*8 + j
// value = B2[ks*32+(lane>>4)*8+j][cg*16+(lane&15)], B2[k][col]=W2[col>>3][k][col&7]
__global__ void k_packW2(const float* __restrict__ W2, u16* __restrict__ hi,
                         u16* __restrict__ lo) {
  int idx = blockIdx.x * 256 + threadIdx.x;
  if (idx >= 4 * 16 * 64 * 8) return;
  int j = idx & 7, lane = (idx >> 3) & 63, ks = (idx >> 9) & 15, cg = idx >> 13;
  int col = cg * 16 + (lane & 15);
  int k = ks * 32 + (lane >> 4) * 8 + j;
  float f = W2[((size_t)(col >> 3) * 512 + k) * 8 + (col & 7)];
  u16 h = f2bf(f);
  hi[idx] = h;
  lo[idx] = f2bf(f - bf2f(h));
}

// GEMM1: [N,128] x [128,512] -> bf16 [N,512]. Block: 64 rows x 512 cols (4 waves).
// Wave w: 4 rowfrags x 8 colfrags (cols w*128..+127). 3-term hi/lo split MFMA.
__global__ __launch_bounds__(256) void k_mgemm1(const u16* __restrict__ ahi,
        const u16* __restrict__ alo, const u16* __restrict__ bhi,
        const u16* __restrict__ blo, u16* __restrict__ H, int N) {
  int w = threadIdx.x >> 6, lane = threadIdx.x & 63;
  int lr = lane & 15, lk = lane >> 4;
  int row0 = blockIdx.x * 64;
  int cg0 = w * 8;
  f32x4 acc[4][8] = {};
  for (int ks = 0; ks < 4; ++ks) {
    bf16x8 Ah[4], Al[4];
    #pragma unroll
    for (int rf = 0; rf < 4; ++rf) {
      int row = row0 + rf * 16 + lr;
      int rc = row < N ? row : 0;
      size_t aidx = (size_t)rc * 128 + ks * 32 + lk * 8;
      Ah[rf] = *reinterpret_cast<const bf16x8*>(&ahi[aidx]);
      Al[rf] = *reinterpret_cast<const bf16x8*>(&alo[aidx]);
    }
    #pragma unroll
    for (int cf = 0; cf < 8; ++cf) {
      size_t bidx = ((size_t)((cg0 + cf) * 4 + ks) * 64 + lane) * 8;
      bf16x8 Bh = *reinterpret_cast<const bf16x8*>(&bhi[bidx]);
      bf16x8 Bl = *reinterpret_cast<const bf16x8*>(&blo[bidx]);
      #pragma unroll
      for (int rf = 0; rf < 4; ++rf) {
        acc[rf][cf] = __builtin_amdgcn_mfma_f32_16x16x32_bf16(Ah[rf], Bh, acc[rf][cf], 0, 0, 0);
        acc[rf][cf] = __builtin_amdgcn_mfma_f32_16x16x32_bf16(Al[rf], Bh, acc[rf][cf], 0, 0, 0);
        acc[rf][cf] = __builtin_amdgcn_mfma_f32_16x16x32_bf16(Ah[rf], Bl, acc[rf][cf], 0, 0, 0);
      }
    }
  }
  #pragma unroll
  for (int rf = 0; rf < 4; ++rf) {
    #pragma unroll
    for (int r = 0; r < 4; ++r) {
      int row = row0 + rf * 16 + lk * 4 + r;
      if (row < N) {
        #pragma unroll
        for (int cf = 0; cf < 8; ++cf)
          H[(size_t)row * 512 + cg0 * 16 + cf * 16 + lr] = f2bf(acc[rf][cf][r]);
      }
    }
  }
}

// GEMM2: [N,512] x [512,64] -> bf16 [N,64]. Block: 128 rows (4 waves x 32 rows).
// Wave: 2 rowfrags x 4 colfrags, K=512 -> 16 ksteps.
__global__ __launch_bounds__(256) void k_mgemm2(const u16* __restrict__ ahi,
        const u16* __restrict__ alo, const u16* __restrict__ bhi,
        const u16* __restrict__ blo, u16* __restrict__ H2, int N) {
  int w = threadIdx.x >> 6, lane = threadIdx.x & 63;
  int lr = lane & 15, lk = lane >> 4;
  int row0 = blockIdx.x * 128 + w * 32;
  f32x4 acc[2][4] = {};
  for (int ks = 0; ks < 16; ++ks) {
    bf16x8 Ah[2], Al[2];
    #pragma unroll
    for (int rf = 0; rf < 2; ++rf) {
      int row = row0 + rf * 16 + lr;
      int rc = row < N ? row : 0;
      size_t aidx = (size_t)rc * 512 + ks * 32 + lk * 8;
      Ah[rf] = *reinterpret_cast<const bf16x8*>(&ahi[aidx]);
      Al[rf] = *reinterpret_cast<const bf16x8*>(&alo[aidx]);
    }
    #pragma unroll
    for (int cf = 0; cf < 4; ++cf) {
      size_t bidx = ((size_t)(cf * 16 + ks) * 64 + lane) * 8;
      bf16x8 Bh = *reinterpret_cast<const bf16x8*>(&bhi[bidx]);
      bf16x8 Bl = *reinterpret_cast<const bf16x8*>(&blo[bidx]);
      #pragma unroll
      for (int rf = 0; rf < 2; ++rf) {
        acc[rf][cf] = __builtin_amdgcn_mfma_f32_16x16x32_bf16(Ah[rf], Bh, acc[rf][cf], 0, 0, 0);
        acc[rf][cf] = __builtin_amdgcn_mfma_f32_16x16x32_bf16(Al[rf], Bh, acc[rf][cf], 0, 0, 0);
        acc[rf][cf] = __builtin_amdgcn_mfma_f32_16x16x32_bf16(Ah[rf], Bl, acc[rf][cf], 0, 0, 0);
      }
    }
  }
  #pragma unroll
  for (int rf = 0; rf < 2; ++rf) {
    #pragma unroll
    for (int r = 0; r < 4; ++r) {
      int row = row0 + rf * 16 + lk * 4 + r;
      if (row < N) {
        #pragma unroll
        for (int cf = 0; cf < 4; ++cf)
          H2[(size_t)row * 64 + cf * 16 + lr] = f2bf(acc[rf][cf][r]);
      }
    }
  }
}

// per (node, head): s_src / s_dst dot products from bf16 H
template <int FH>
__global__ void k_scores(const u16* __restrict__ H, const float* __restrict__ a,
                         float* __restrict__ ss, float* __restrict__ sd,
                         int n, int Cout) {
  int i = blockIdx.x * blockDim.x + threadIdx.x;
  if (i >= n * TNHEADS) return;
  int node = i >> 3, h = i & 7;
  const uint4* hp = reinterpret_cast<const uint4*>(H + (size_t)node * Cout + h * FH);
  const float* as = a + h * 2 * FH;
  float s0 = 0.f, s1v = 0.f;
  #pragma unroll
  for (int k = 0; k < FH / 8; ++k) {
    uint4 v = hp[k];
    u32 wv[4] = {v.x, v.y, v.z, v.w};
    #pragma unroll
    for (int q = 0; q < 4; q++) {
      float lo = bf2f((u16)(wv[q] & 0xffff));
      float hi = bf2f((u16)(wv[q] >> 16));
      int base = k * 8 + q * 2;
      s0  += lo * as[base]      + hi * as[base + 1];
      s1v += lo * as[FH + base] + hi * as[FH + base + 1];
    }
  }
  ss[i] = s0;
  sd[i] = s1v;
}

// Layer-1 aggregation: one wave per node; lane covers 8 bf16 feats (head = lane>>3).
// Output written as bf16 hi/lo pair (feeds MFMA GEMM2 at ~fp32 precision).
__global__ __launch_bounds__(256) void k_agg1(const u16* __restrict__ H,
        const float* __restrict__ ss, const float* __restrict__ sd,
        const int* __restrict__ offs, const int* __restrict__ adj,
        u16* __restrict__ o_hi, u16* __restrict__ o_lo, int n) {
  int node = (blockIdx.x * 256 + threadIdx.x) >> 6;
  int lane = threadIdx.x & 63;
  if (node >= n) return;
  int head = lane >> 3;
  int beg = offs[node], end = offs[node + 1];
  float sS = ss[node * 8 + head];
  const uint4* Hv = reinterpret_cast<const uint4*>(H);  // 64 uint4 per row
  float acc[8] = {};
  float rsum = 0.f;
  for (int e = beg; e < end; e += 8) {
    int m = end - e; if (m > 8) m = 8;
    int li = lane & 7; if (li >= m) li = m - 1;
    int dl = adj[e + li];
    int dr[8];
    #pragma unroll
    for (int i = 0; i < 8; i++) dr[i] = __shfl(dl, i);
    float sdv[8];
    uint4 rv[8];
    #pragma unroll
    for (int i = 0; i < 8; i++) {
      if (i < m) {
        sdv[i] = sd[dr[i] * 8 + head];
        rv[i] = Hv[(size_t)dr[i] * 64 + lane];
      }
    }
    #pragma unroll
    for (int i = 0; i < 8; i++) {
      if (i < m) {
        float z = sS + sdv[i];
        float w = __expf(-(z > 0.f ? z : 0.2f * z));
        rsum += w;
        u32 w0 = rv[i].x, w1 = rv[i].y, w2 = rv[i].z, w3 = rv[i].w;
        acc[0] = fmaf(w, bf2f((u16)(w0 & 0xffff)), acc[0]);
        acc[1] = fmaf(w, bf2f((u16)(w0 >> 16)),    acc[1]);
        acc[2] = fmaf(w, bf2f((u16)(w1 & 0xffff)), acc[2]);
        acc[3] = fmaf(w, bf2f((u16)(w1 >> 16)),    acc[3]);
        acc[4] = fmaf(w, bf2f((u16)(w2 & 0xffff)), acc[4]);
        acc[5] = fmaf(w, bf2f((u16)(w2 >> 16)),    acc[5]);
        acc[6] = fmaf(w, bf2f((u16)(w3 & 0xffff)), acc[6]);
        acc[7] = fmaf(w, bf2f((u16)(w3 >> 16)),    acc[7]);
      }
    }
  }
  float inv = 1.f / rsum;
  u16 oh[8], ol[8];
  #pragma unroll
  for (int k = 0; k < 8; k++) {
    float v = acc[k] * inv;
    v = v > 0.f ? v : expm1f(v);
    u16 hb = f2bf(v);
    oh[k] = hb;
    ol[k] = f2bf(v - bf2f(hb));
  }
  uint4 ph, pl;
  ph.x = (u32)oh[0] | ((u32)oh[1] << 16); ph.y = (u32)oh[2] | ((u32)oh[3] << 16);
  ph.z = (u32)oh[4] | ((u32)oh[5] << 16); ph.w = (u32)oh[6] | ((u32)oh[7] << 16);
  pl.x = (u32)ol[0] | ((u32)ol[1] << 16); pl.y = (u32)ol[2] | ((u32)ol[3] << 16);
  pl.z = (u32)ol[4] | ((u32)ol[5] << 16); pl.w = (u32)ol[6] | ((u32)ol[7] << 16);
  reinterpret_cast<uint4*>(o_hi)[(size_t)node * 64 + lane] = ph;
  reinterpret_cast<uint4*>(o_lo)[(size_t)node * 64 + lane] = pl;
}

// Layer-2 aggregation: one wave per node; 8 edges per iter; final fp32 out.
__global__ __launch_bounds__(256) void k_agg2(const u16* __restrict__ H,
        const float* __restrict__ ss, const float* __restrict__ sd,
        const int* __restrict__ offs, const int* __restrict__ adj,
        float* __restrict__ outp, int n) {
  int node = (blockIdx.x * 256 + threadIdx.x) >> 6;
  int lane = threadIdx.x & 63;
  if (node >= n) return;
  int li = lane >> 3, fg = lane & 7;
  int beg = offs[node], end = offs[node + 1];
  float sS = ss[node * 8 + fg];
  const uint4* Hv = reinterpret_cast<const uint4*>(H);  // 8 uint4 per row
  float acc[8] = {};
  float rsum = 0.f;
  for (int e = beg; e < end; e += 8) {
    int m = end - e; if (m > 8) m = 8;
    int ll = lane & 7; if (ll >= m) ll = m - 1;
    int dl = adj[e + ll];
    int d = __shfl(dl, li);
    if (li < m) {
      float sdv = sd[d * 8 + fg];
      uint4 rv = Hv[(size_t)d * 8 + fg];
      float z = sS + sdv;
      float w = __expf(-(z > 0.f ? z : 0.2f * z));
      rsum += w;
      u32 w0 = rv.x, w1 = rv.y, w2 = rv.z, w3 = rv.w;
      acc[0] = fmaf(w, bf2f((u16)(w0 & 0xffff)), acc[0]);
      acc[1] = fmaf(w, bf2f((u16)(w0 >> 16)),    acc[1]);
      acc[2] = fmaf(w, bf2f((u16)(w1 & 0xffff)), acc[2]);
      acc[3] = fmaf(w, bf2f((u16)(w1 >> 16)),    acc[3]);
      acc[4] = fmaf(w, bf2f((u16)(w2 & 0xffff)), acc[4]);
      acc[5] = fmaf(w, bf2f((u16)(w2 >> 16)),    acc[5]);
      acc[6] = fmaf(w, bf2f((u16)(w3 & 0xffff)), acc[6]);
      acc[7] = fmaf(w, bf2f((u16)(w3 >> 16)),    acc[7]);
    }
  }
  #pragma unroll
  for (int mask = 8; mask < 64; mask <<= 1) {
    rsum += __shfl_xor(rsum, mask);
    #pragma unroll
    for (int k = 0; k < 8; k++) acc[k] += __shfl_xor(acc[k], mask);
  }
  if (li == 0) {
    float inv = 1.f / rsum;
    float o[8];
    #pragma unroll
    for (int k = 0; k < 8; k++) {
      float v = acc[k] * inv;
      o[k] = v > 0.f ? v : expm1f(v);
    }
    float4* Ov = reinterpret_cast<float4*>(outp);
    Ov[(size_t)node * 16 + fg * 2]     = make_float4(o[0], o[1], o[2], o[3]);
    Ov[(size_t)node * 16 + fg * 2 + 1] = make_float4(o[4], o[5], o[6], o[7]);
  }
}

extern "C" void kernel_launch(void* const* d_in, const int* in_sizes, int n_in,
                              void* d_out, int out_size, void* d_ws, size_t ws_size,
                              hipStream_t stream) {
  const float* x  = (const float*)d_in[0];
  const int*   ei = (const int*)d_in[1];
  const float* W1 = (const float*)d_in[2];
  const float* a1 = (const float*)d_in[3];
  const float* W2 = (const float*)d_in[4];
  const float* a2 = (const float*)d_in[5];
  float* out = (float*)d_out;

  int N = in_sizes[0] / TNFEAT;   // 50000
  int E = in_sizes[1] / 2;        // 850000
  const int* src = ei;
  const int* dst = ei + E;
  int NB = (N + 1023) / 1024;     // scan blocks

  char* base = (char*)d_ws;
  size_t off = 0;
  auto take = [&](size_t bytes) { char* p = base + off; off = (off + bytes + 255) & ~(size_t)255; return p; };
  u16*   h_all = (u16*)take((size_t)N * C1 * 2);
  u16*   h1hi  = (u16*)take((size_t)N * C1 * 2);
  u16*   h1lo  = (u16*)take((size_t)N * C1 * 2);
  u16*   h2p   = (u16*)take((size_t)N * C2 * 2);
  u16*   xhi   = (u16*)take((size_t)N * TNFEAT * 2);
  u16*   xlo   = (u16*)take((size_t)N * TNFEAT * 2);
  u16*   w1hi  = (u16*)take(65536 * 2);
  u16*   w1lo  = (u16*)take(65536 * 2);
  u16*   w2hi  = (u16*)take(32768 * 2);
  u16*   w2lo  = (u16*)take(32768 * 2);
  float* s1s   = (float*)take((size_t)N * 8 * 4);
  float* s1d   = (float*)take((size_t)N * 8 * 4);
  float* s2s   = (float*)take((size_t)N * 8 * 4);
  float* s2d   = (float*)take((size_t)N * 8 * 4);
  int*   deg   = (int*)take((size_t)N * 4);
  int*   offs  = (int*)take((size_t)(N + 1) * 4);
  int*   cur   = (int*)take((size_t)N * 4);
  int*   loc   = (int*)take((size_t)N * 4);
  int*   bsum  = (int*)take(64 * 4);
  int*   adj   = (int*)take((size_t)E * 4);

  // CSR build (by src)
  hipLaunchKernelGGL(k_zero, dim3((N + 255) / 256), dim3(256), 0, stream, deg, N);
  hipLaunchKernelGGL(k_hist, dim3((E + 255) / 256), dim3(256), 0, stream, src, deg, E);
  hipLaunchKernelGGL(k_bscan1, dim3(NB), dim3(1024), 0, stream, deg, loc, bsum, N);
  hipLaunchKernelGGL(k_bscan2, dim3(1), dim3(64), 0, stream, bsum, NB);
  hipLaunchKernelGGL(k_offs, dim3(NB), dim3(1024), 0, stream, loc, bsum, offs, N);
  hipLaunchKernelGGL(k_copy, dim3((N + 255) / 256), dim3(256), 0, stream, offs, cur, N);
  hipLaunchKernelGGL(k_fill, dim3((E + 255) / 256), dim3(256), 0, stream, src, dst, cur, adj, E);

  // Precision-split inputs + pack weights into fragment order
  int n4 = N * TNFEAT / 4;
  hipLaunchKernelGGL(k_split, dim3((n4 + 255) / 256), dim3(256), 0, stream, x, xhi, xlo, n4);
  hipLaunchKernelGGL(k_packW1, dim3(256), dim3(256), 0, stream, W1, w1hi, w1lo);
  hipLaunchKernelGGL(k_packW2, dim3(128), dim3(256), 0, stream, W2, w2hi, w2lo);

  // Layer 1
  hipLaunchKernelGGL(k_mgemm1, dim3((N + 63) / 64), dim3(256), 0, stream,
                     xhi, xlo, w1hi, w1lo, h_all, N);
  hipLaunchKernelGGL((k_scores<64>), dim3((N * 8 + 255) / 256), dim3(256), 0, stream,
                     h_all, a1, s1s, s1d, N, C1);
  hipLaunchKernelGGL(k_agg1, dim3((N + 3) / 4), dim3(256), 0, stream,
                     h_all, s1s, s1d, offs, adj, h1hi, h1lo, N);

  // Layer 2
  hipLaunchKernelGGL(k_mgemm2, dim3((N + 127) / 128), dim3(256), 0, stream,
                     h1hi, h1lo, w2hi, w2lo, h2p, N);
  hipLaunchKernelGGL((k_scores<8>), dim3((N * 8 + 255) / 256), dim3(256), 0, stream,
                     h2p, a2, s2s, s2d, N, C2);
  hipLaunchKernelGGL(k_agg2, dim3((N + 3) / 4), dim3(256), 0, stream,
                     h2p, s2s, s2d, offs, adj, out, N);
}

// Round 5
// 398.758 us; speedup vs baseline: 2.9883x; 1.0544x over previous
//
#include <hip/hip_runtime.h>
#include <math.h>

typedef unsigned int u32;
typedef unsigned short u16;
typedef __attribute__((ext_vector_type(8))) short bf16x8;
typedef __attribute__((ext_vector_type(4))) float f32x4;

static constexpr int TNFEAT  = 128;
static constexpr int TNHEADS = 8;
static constexpr int C1      = 512;  // NHID*NHEADS
static constexpr int C2      = 64;   // NCLASS

__device__ inline float bf2f(u16 u) {
  union { u32 i; float f; } c; c.i = ((u32)u) << 16; return c.f;
}
__device__ inline u16 f2bf(float f) {
  union { float f; u32 i; } c; c.f = f;
  u32 r = c.i + 0x7FFF + ((c.i >> 16) & 1);   // round-nearest-even
  return (u16)(r >> 16);
}
__device__ inline uint4 ld16(const u16* base, u32 byteoff) {
  return *reinterpret_cast<const uint4*>(reinterpret_cast<const char*>(base) + byteoff);
}

__global__ void k_zero(int* __restrict__ p, int n) {
  int i = blockIdx.x * blockDim.x + threadIdx.x;
  if (i < n) p[i] = 0;
}

__global__ void k_hist(const int* __restrict__ src, int* __restrict__ deg, int E) {
  int i = blockIdx.x * blockDim.x + threadIdx.x;
  if (i < E) atomicAdd(&deg[src[i]], 1);
}

__global__ __launch_bounds__(1024) void k_bscan1(const int* __restrict__ deg,
                                                 int* __restrict__ loc,
                                                 int* __restrict__ bsum, int n) {
  __shared__ int sdata[1024];
  int t = threadIdx.x;
  int i = blockIdx.x * 1024 + t;
  int v = (i < n) ? deg[i] : 0;
  sdata[t] = v;
  __syncthreads();
  for (int ofs = 1; ofs < 1024; ofs <<= 1) {
    int tv = (t >= ofs) ? sdata[t - ofs] : 0;
    __syncthreads();
    sdata[t] += tv;
    __syncthreads();
  }
  if (i < n) loc[i] = sdata[t];
  if (t == 1023) bsum[blockIdx.x] = sdata[1023];
}

__global__ void k_bscan2(int* __restrict__ bsum, int nb) {
  int t = threadIdx.x;
  int v = (t < nb) ? bsum[t] : 0;
  #pragma unroll
  for (int ofs = 1; ofs < 64; ofs <<= 1) {
    int u = __shfl_up(v, ofs);
    if (t >= ofs) v += u;
  }
  if (t < nb) bsum[t] = v;
}

// offs[i+1] = loc[i] + prefix(block); cur[i] = offs[i+1] - deg[i] (fused k_copy)
__global__ __launch_bounds__(1024) void k_offs(const int* __restrict__ loc,
                                               const int* __restrict__ bsum,
                                               const int* __restrict__ deg,
                                               int* __restrict__ offs,
                                               int* __restrict__ cur, int n) {
  int b = blockIdx.x;
  int i = b * 1024 + threadIdx.x;
  int base = (b > 0) ? bsum[b - 1] : 0;
  if (i < n) {
    int v = base + loc[i];
    offs[i + 1] = v;
    cur[i] = v - deg[i];
  }
  if (i == 0) offs[0] = 0;
}

__global__ void k_fill(const int* __restrict__ src, const int* __restrict__ dst,
                       int* __restrict__ cur, int* __restrict__ adj, int E) {
  int i = blockIdx.x * blockDim.x + threadIdx.x;
  if (i < E) {
    int p = atomicAdd(&cur[src[i]], 1);
    adj[p] = dst[i];
  }
}

// fp32 -> (bf16 hi, bf16 lo), 4 elems/thread
__global__ void k_split(const float* __restrict__ in, u16* __restrict__ hi,
                        u16* __restrict__ lo, int n4) {
  int i = blockIdx.x * blockDim.x + threadIdx.x;
  if (i >= n4) return;
  float4 v = reinterpret_cast<const float4*>(in)[i];
  float f[4] = {v.x, v.y, v.z, v.w};
  ushort4 h, l;
  u16* hp = &h.x; u16* lp = &l.x;
  #pragma unroll
  for (int k = 0; k < 4; k++) {
    u16 hb = f2bf(f[k]);
    hp[k] = hb;
    lp[k] = f2bf(f[k] - bf2f(hb));
  }
  reinterpret_cast<ushort4*>(hi)[i] = h;
  reinterpret_cast<ushort4*>(lo)[i] = l;
}

// Pack W1 [8][128][64] into MFMA b-frag order
__global__ void k_packW1(const float* __restrict__ W1, u16* __restrict__ hi,
                         u16* __restrict__ lo) {
  int idx = blockIdx.x * 256 + threadIdx.x;
  if (idx >= 32 * 4 * 64 * 8) return;
  int j = idx & 7, lane = (idx >> 3) & 63, ks = (idx >> 9) & 3, cg = idx >> 11;
  int col = cg * 16 + (lane & 15);
  int k = ks * 32 + (lane >> 4) * 8 + j;
  float f = W1[((size_t)(col >> 6) * 128 + k) * 64 + (col & 63)];
  u16 h = f2bf(f);
  hi[idx] = h;
  lo[idx] = f2bf(f - bf2f(h));
}

// Pack W2 [8][512][8]
__global__ void k_packW2(const float* __restrict__ W2, u16* __restrict__ hi,
                         u16* __restrict__ lo) {
  int idx = blockIdx.x * 256 + threadIdx.x;
  if (idx >= 4 * 16 * 64 * 8) return;
  int j = idx & 7, lane = (idx >> 3) & 63, ks = (idx >> 9) & 15, cg = idx >> 13;
  int col = cg * 16 + (lane & 15);
  int k = ks * 32 + (lane >> 4) * 8 + j;
  float f = W2[((size_t)(col >> 3) * 512 + k) * 8 + (col & 7)];
  u16 h = f2bf(f);
  hi[idx] = h;
  lo[idx] = f2bf(f - bf2f(h));
}

// GEMM1: [N,128] x [128,512] -> bf16 [N,512]. Block: 64 rows x 512 cols (4 waves).
__global__ __launch_bounds__(256) void k_mgemm1(const u16* __restrict__ ahi,
        const u16* __restrict__ alo, const u16* __restrict__ bhi,
        const u16* __restrict__ blo, u16* __restrict__ H, int N) {
  int w = threadIdx.x >> 6, lane = threadIdx.x & 63;
  int lr = lane & 15, lk = lane >> 4;
  int row0 = blockIdx.x * 64;
  int cg0 = w * 8;
  f32x4 acc[4][8] = {};
  for (int ks = 0; ks < 4; ++ks) {
    bf16x8 Ah[4], Al[4];
    #pragma unroll
    for (int rf = 0; rf < 4; ++rf) {
      int row = row0 + rf * 16 + lr;
      int rc = row < N ? row : 0;
      size_t aidx = (size_t)rc * 128 + ks * 32 + lk * 8;
      Ah[rf] = *reinterpret_cast<const bf16x8*>(&ahi[aidx]);
      Al[rf] = *reinterpret_cast<const bf16x8*>(&alo[aidx]);
    }
    #pragma unroll
    for (int cf = 0; cf < 8; ++cf) {
      size_t bidx = ((size_t)((cg0 + cf) * 4 + ks) * 64 + lane) * 8;
      bf16x8 Bh = *reinterpret_cast<const bf16x8*>(&bhi[bidx]);
      bf16x8 Bl = *reinterpret_cast<const bf16x8*>(&blo[bidx]);
      #pragma unroll
      for (int rf = 0; rf < 4; ++rf) {
        acc[rf][cf] = __builtin_amdgcn_mfma_f32_16x16x32_bf16(Ah[rf], Bh, acc[rf][cf], 0, 0, 0);
        acc[rf][cf] = __builtin_amdgcn_mfma_f32_16x16x32_bf16(Al[rf], Bh, acc[rf][cf], 0, 0, 0);
        acc[rf][cf] = __builtin_amdgcn_mfma_f32_16x16x32_bf16(Ah[rf], Bl, acc[rf][cf], 0, 0, 0);
      }
    }
  }
  #pragma unroll
  for (int rf = 0; rf < 4; ++rf) {
    #pragma unroll
    for (int r = 0; r < 4; ++r) {
      int row = row0 + rf * 16 + lk * 4 + r;
      if (row < N) {
        #pragma unroll
        for (int cf = 0; cf < 8; ++cf)
          H[(size_t)row * 512 + cg0 * 16 + cf * 16 + lr] = f2bf(acc[rf][cf][r]);
      }
    }
  }
}

// GEMM2: bf16 [N,512] x [512,64] -> bf16 [N,64]. A single-precision bf16, B hi/lo.
__global__ __launch_bounds__(256) void k_mgemm2(const u16* __restrict__ A,
        const u16* __restrict__ bhi, const u16* __restrict__ blo,
        u16* __restrict__ H2, int N) {
  int w = threadIdx.x >> 6, lane = threadIdx.x & 63;
  int lr = lane & 15, lk = lane >> 4;
  int row0 = blockIdx.x * 128 + w * 32;
  f32x4 acc[2][4] = {};
  for (int ks = 0; ks < 16; ++ks) {
    bf16x8 Ah[2];
    #pragma unroll
    for (int rf = 0; rf < 2; ++rf) {
      int row = row0 + rf * 16 + lr;
      int rc = row < N ? row : 0;
      size_t aidx = (size_t)rc * 512 + ks * 32 + lk * 8;
      Ah[rf] = *reinterpret_cast<const bf16x8*>(&A[aidx]);
    }
    #pragma unroll
    for (int cf = 0; cf < 4; ++cf) {
      size_t bidx = ((size_t)(cf * 16 + ks) * 64 + lane) * 8;
      bf16x8 Bh = *reinterpret_cast<const bf16x8*>(&bhi[bidx]);
      bf16x8 Bl = *reinterpret_cast<const bf16x8*>(&blo[bidx]);
      #pragma unroll
      for (int rf = 0; rf < 2; ++rf) {
        acc[rf][cf] = __builtin_amdgcn_mfma_f32_16x16x32_bf16(Ah[rf], Bh, acc[rf][cf], 0, 0, 0);
        acc[rf][cf] = __builtin_amdgcn_mfma_f32_16x16x32_bf16(Ah[rf], Bl, acc[rf][cf], 0, 0, 0);
      }
    }
  }
  #pragma unroll
  for (int rf = 0; rf < 2; ++rf) {
    #pragma unroll
    for (int r = 0; r < 4; ++r) {
      int row = row0 + rf * 16 + lk * 4 + r;
      if (row < N) {
        #pragma unroll
        for (int cf = 0; cf < 4; ++cf)
          H2[(size_t)row * 64 + cf * 16 + lr] = f2bf(acc[rf][cf][r]);
      }
    }
  }
}

// per (node, head): s_src / s_dst dot products from bf16 H
template <int FH>
__global__ void k_scores(const u16* __restrict__ H, const float* __restrict__ a,
                         float* __restrict__ ss, float* __restrict__ sd,
                         int n, int Cout) {
  int i = blockIdx.x * blockDim.x + threadIdx.x;
  if (i >= n * TNHEADS) return;
  int node = i >> 3, h = i & 7;
  const uint4* hp = reinterpret_cast<const uint4*>(H + (size_t)node * Cout + h * FH);
  const float* as = a + h * 2 * FH;
  float s0 = 0.f, s1v = 0.f;
  #pragma unroll
  for (int k = 0; k < FH / 8; ++k) {
    uint4 v = hp[k];
    u32 wv[4] = {v.x, v.y, v.z, v.w};
    #pragma unroll
    for (int q = 0; q < 4; q++) {
      float lo = bf2f((u16)(wv[q] & 0xffff));
      float hi = bf2f((u16)(wv[q] >> 16));
      int base = k * 8 + q * 2;
      s0  += lo * as[base]      + hi * as[base + 1];
      s1v += lo * as[FH + base] + hi * as[FH + base + 1];
    }
  }
  ss[i] = s0;
  sd[i] = s1v;
}

#define ACC8(W, RV)                                            \
  do {                                                         \
    u32 w0 = (RV).x, w1 = (RV).y, w2 = (RV).z, w3 = (RV).w;    \
    acc[0] = fmaf((W), bf2f((u16)(w0 & 0xffff)), acc[0]);      \
    acc[1] = fmaf((W), bf2f((u16)(w0 >> 16)),    acc[1]);      \
    acc[2] = fmaf((W), bf2f((u16)(w1 & 0xffff)), acc[2]);      \
    acc[3] = fmaf((W), bf2f((u16)(w1 >> 16)),    acc[3]);      \
    acc[4] = fmaf((W), bf2f((u16)(w2 & 0xffff)), acc[4]);      \
    acc[5] = fmaf((W), bf2f((u16)(w2 >> 16)),    acc[5]);      \
    acc[6] = fmaf((W), bf2f((u16)(w3 & 0xffff)), acc[6]);      \
    acc[7] = fmaf((W), bf2f((u16)(w3 >> 16)),    acc[7]);      \
  } while (0)

// Layer-1 aggregation: one wave per node; lane covers 8 bf16 feats (head = lane>>3).
// Main loop = unpredicated 8-edge blocks; u32 byte addressing. bf16 output.
__global__ __launch_bounds__(256) void k_agg1(const u16* __restrict__ H,
        const float* __restrict__ ss, const float* __restrict__ sd,
        const int* __restrict__ offs, const int* __restrict__ adj,
        u16* __restrict__ o1, int n) {
  int node = (blockIdx.x * 256 + threadIdx.x) >> 6;
  int lane = threadIdx.x & 63;
  if (node >= n) return;
  int head = lane >> 3;
  int beg = offs[node], end = offs[node + 1];
  float sS = ss[node * 8 + head];
  float acc[8] = {};
  float rsum = 0.f;
  int e = beg;
  for (; e + 8 <= end; e += 8) {
    int dl = adj[e + (lane & 7)];
    int dr[8];
    #pragma unroll
    for (int i = 0; i < 8; i++) dr[i] = __shfl(dl, i);
    float sdv[8];
    uint4 rv[8];
    #pragma unroll
    for (int i = 0; i < 8; i++) {
      u32 d = (u32)dr[i];
      sdv[i] = sd[d * 8u + head];
      rv[i] = ld16(H, d * 1024u + lane * 16u);
    }
    #pragma unroll
    for (int i = 0; i < 8; i++) {
      float z = sS + sdv[i];
      float w = __expf(-(z > 0.f ? z : 0.2f * z));
      rsum += w;
      ACC8(w, rv[i]);
    }
  }
  if (e < end) {
    int m = end - e;
    int li = lane & 7; if (li >= m) li = m - 1;
    int dl = adj[e + li];
    int dr[8];
    #pragma unroll
    for (int i = 0; i < 8; i++) dr[i] = __shfl(dl, i);
    float sdv[8];
    uint4 rv[8];
    #pragma unroll
    for (int i = 0; i < 8; i++) {
      if (i < m) {
        u32 d = (u32)dr[i];
        sdv[i] = sd[d * 8u + head];
        rv[i] = ld16(H, d * 1024u + lane * 16u);
      }
    }
    #pragma unroll
    for (int i = 0; i < 8; i++) {
      if (i < m) {
        float z = sS + sdv[i];
        float w = __expf(-(z > 0.f ? z : 0.2f * z));
        rsum += w;
        ACC8(w, rv[i]);
      }
    }
  }
  float inv = 1.f / rsum;
  u16 oh[8];
  #pragma unroll
  for (int k = 0; k < 8; k++) {
    float v = acc[k] * inv;
    v = v > 0.f ? v : expm1f(v);
    oh[k] = f2bf(v);
  }
  uint4 ph;
  ph.x = (u32)oh[0] | ((u32)oh[1] << 16); ph.y = (u32)oh[2] | ((u32)oh[3] << 16);
  ph.z = (u32)oh[4] | ((u32)oh[5] << 16); ph.w = (u32)oh[6] | ((u32)oh[7] << 16);
  reinterpret_cast<uint4*>(o1)[(size_t)node * 64 + lane] = ph;
}

// Layer-2 aggregation: one wave per node; 8 edges per iter; final fp32 out.
__global__ __launch_bounds__(256) void k_agg2(const u16* __restrict__ H,
        const float* __restrict__ ss, const float* __restrict__ sd,
        const int* __restrict__ offs, const int* __restrict__ adj,
        float* __restrict__ outp, int n) {
  int node = (blockIdx.x * 256 + threadIdx.x) >> 6;
  int lane = threadIdx.x & 63;
  if (node >= n) return;
  int li = lane >> 3, fg = lane & 7;
  int beg = offs[node], end = offs[node + 1];
  float sS = ss[node * 8 + fg];
  float acc[8] = {};
  float rsum = 0.f;
  int e = beg;
  for (; e + 8 <= end; e += 8) {
    int dl = adj[e + (lane & 7)];
    u32 d = (u32)__shfl(dl, li);
    float sdv = sd[d * 8u + fg];
    uint4 rv = ld16(H, d * 128u + fg * 16u);
    float z = sS + sdv;
    float w = __expf(-(z > 0.f ? z : 0.2f * z));
    rsum += w;
    ACC8(w, rv);
  }
  if (e < end) {
    int m = end - e;
    int ll = lane & 7; if (ll >= m) ll = m - 1;
    int dl = adj[e + ll];
    u32 d = (u32)__shfl(dl, li);
    if (li < m) {
      float sdv = sd[d * 8u + fg];
      uint4 rv = ld16(H, d * 128u + fg * 16u);
      float z = sS + sdv;
      float w = __expf(-(z > 0.f ? z : 0.2f * z));
      rsum += w;
      ACC8(w, rv);
    }
  }
  #pragma unroll
  for (int mask = 8; mask < 64; mask <<= 1) {
    rsum += __shfl_xor(rsum, mask);
    #pragma unroll
    for (int k = 0; k < 8; k++) acc[k] += __shfl_xor(acc[k], mask);
  }
  if (li == 0) {
    float inv = 1.f / rsum;
    float o[8];
    #pragma unroll
    for (int k = 0; k < 8; k++) {
      float v = acc[k] * inv;
      o[k] = v > 0.f ? v : expm1f(v);
    }
    float4* Ov = reinterpret_cast<float4*>(outp);
    Ov[(size_t)node * 16 + fg * 2]     = make_float4(o[0], o[1], o[2], o[3]);
    Ov[(size_t)node * 16 + fg * 2 + 1] = make_float4(o[4], o[5], o[6], o[7]);
  }
}

extern "C" void kernel_launch(void* const* d_in, const int* in_sizes, int n_in,
                              void* d_out, int out_size, void* d_ws, size_t ws_size,
                              hipStream_t stream) {
  const float* x  = (const float*)d_in[0];
  const int*   ei = (const int*)d_in[1];
  const float* W1 = (const float*)d_in[2];
  const float* a1 = (const float*)d_in[3];
  const float* W2 = (const float*)d_in[4];
  const float* a2 = (const float*)d_in[5];
  float* out = (float*)d_out;

  int N = in_sizes[0] / TNFEAT;   // 50000
  int E = in_sizes[1] / 2;        // 850000
  const int* src = ei;
  const int* dst = ei + E;
  int NB = (N + 1023) / 1024;     // scan blocks

  char* base = (char*)d_ws;
  size_t off = 0;
  auto take = [&](size_t bytes) { char* p = base + off; off = (off + bytes + 255) & ~(size_t)255; return p; };
  u16*   h_all = (u16*)take((size_t)N * C1 * 2);
  u16*   h1    = (u16*)take((size_t)N * C1 * 2);
  u16*   h2p   = (u16*)take((size_t)N * C2 * 2);
  u16*   xhi   = (u16*)take((size_t)N * TNFEAT * 2);
  u16*   xlo   = (u16*)take((size_t)N * TNFEAT * 2);
  u16*   w1hi  = (u16*)take(65536 * 2);
  u16*   w1lo  = (u16*)take(65536 * 2);
  u16*   w2hi  = (u16*)take(32768 * 2);
  u16*   w2lo  = (u16*)take(32768 * 2);
  float* s1s   = (float*)take((size_t)N * 8 * 4);
  float* s1d   = (float*)take((size_t)N * 8 * 4);
  float* s2s   = (float*)take((size_t)N * 8 * 4);
  float* s2d   = (float*)take((size_t)N * 8 * 4);
  int*   deg   = (int*)take((size_t)N * 4);
  int*   offs  = (int*)take((size_t)(N + 1) * 4);
  int*   cur   = (int*)take((size_t)N * 4);
  int*   loc   = (int*)take((size_t)N * 4);
  int*   bsum  = (int*)take(64 * 4);
  int*   adj   = (int*)take((size_t)E * 4);

  // CSR build (by src)
  hipLaunchKernelGGL(k_zero, dim3((N + 255) / 256), dim3(256), 0, stream, deg, N);
  hipLaunchKernelGGL(k_hist, dim3((E + 255) / 256), dim3(256), 0, stream, src, deg, E);
  hipLaunchKernelGGL(k_bscan1, dim3(NB), dim3(1024), 0, stream, deg, loc, bsum, N);
  hipLaunchKernelGGL(k_bscan2, dim3(1), dim3(64), 0, stream, bsum, NB);
  hipLaunchKernelGGL(k_offs, dim3(NB), dim3(1024), 0, stream, loc, bsum, deg, offs, cur, N);
  hipLaunchKernelGGL(k_fill, dim3((E + 255) / 256), dim3(256), 0, stream, src, dst, cur, adj, E);

  // Precision-split inputs + pack weights into fragment order
  int n4 = N * TNFEAT / 4;
  hipLaunchKernelGGL(k_split, dim3((n4 + 255) / 256), dim3(256), 0, stream, x, xhi, xlo, n4);
  hipLaunchKernelGGL(k_packW1, dim3(256), dim3(256), 0, stream, W1, w1hi, w1lo);
  hipLaunchKernelGGL(k_packW2, dim3(128), dim3(256), 0, stream, W2, w2hi, w2lo);

  // Layer 1
  hipLaunchKernelGGL(k_mgemm1, dim3((N + 63) / 64), dim3(256), 0, stream,
                     xhi, xlo, w1hi, w1lo, h_all, N);
  hipLaunchKernelGGL((k_scores<64>), dim3((N * 8 + 255) / 256), dim3(256), 0, stream,
                     h_all, a1, s1s, s1d, N, C1);
  hipLaunchKernelGGL(k_agg1, dim3((N + 3) / 4), dim3(256), 0, stream,
                     h_all, s1s, s1d, offs, adj, h1, N);

  // Layer 2
  hipLaunchKernelGGL(k_mgemm2, dim3((N + 127) / 128), dim3(256), 0, stream,
                     h1, w2hi, w2lo, h2p, N);
  hipLaunchKernelGGL((k_scores<8>), dim3((N * 8 + 255) / 256), dim3(256), 0, stream,
                     h2p, a2, s2s, s2d, N, C2);
  hipLaunchKernelGGL(k_agg2, dim3((N + 3) / 4), dim3(256), 0, stream,
                     h2p, s2s, s2d, offs, adj, out, N);
}

// Round 6
// 361.506 us; speedup vs baseline: 3.2962x; 1.1030x over previous
//
#include <hip/hip_runtime.h>
#include <math.h>

typedef unsigned int u32;
typedef unsigned short u16;
typedef __attribute__((ext_vector_type(8))) short bf16x8;
typedef __attribute__((ext_vector_type(4))) float f32x4;
typedef __attribute__((ext_vector_type(2))) float f32x2;

static constexpr int TNFEAT  = 128;
static constexpr int TNHEADS = 8;
static constexpr int C1      = 512;  // NHID*NHEADS
static constexpr int C2      = 64;   // NCLASS

__device__ inline float bf2f(u16 u) {
  union { u32 i; float f; } c; c.i = ((u32)u) << 16; return c.f;
}
__device__ inline float bitsf(u32 u) {
  union { u32 i; float f; } c; c.i = u; return c.f;
}
__device__ inline u16 f2bf(float f) {
  union { float f; u32 i; } c; c.f = f;
  u32 r = c.i + 0x7FFF + ((c.i >> 16) & 1);   // round-nearest-even
  return (u16)(r >> 16);
}
// hardware packed f32->bf16 convert (1 VALU op for 2 elements)
__device__ inline u32 cvt_pk_bf16(float lo, float hi) {
  u32 r;
  asm volatile("v_cvt_pk_bf16_f32 %0, %1, %2" : "=v"(r) : "v"(lo), "v"(hi));
  return r;
}
__device__ inline uint4 ld16(const u16* base, u32 byteoff) {
  return *reinterpret_cast<const uint4*>(reinterpret_cast<const char*>(base) + byteoff);
}

__global__ void k_zero(int* __restrict__ p, int n) {
  int i = blockIdx.x * blockDim.x + threadIdx.x;
  if (i < n) p[i] = 0;
}

__global__ void k_hist(const int* __restrict__ src, int* __restrict__ deg, int E) {
  int i = blockIdx.x * blockDim.x + threadIdx.x;
  if (i < E) atomicAdd(&deg[src[i]], 1);
}

__global__ __launch_bounds__(1024) void k_bscan1(const int* __restrict__ deg,
                                                 int* __restrict__ loc,
                                                 int* __restrict__ bsum, int n) {
  __shared__ int sdata[1024];
  int t = threadIdx.x;
  int i = blockIdx.x * 1024 + t;
  int v = (i < n) ? deg[i] : 0;
  sdata[t] = v;
  __syncthreads();
  for (int ofs = 1; ofs < 1024; ofs <<= 1) {
    int tv = (t >= ofs) ? sdata[t - ofs] : 0;
    __syncthreads();
    sdata[t] += tv;
    __syncthreads();
  }
  if (i < n) loc[i] = sdata[t];
  if (t == 1023) bsum[blockIdx.x] = sdata[1023];
}

__global__ void k_bscan2(int* __restrict__ bsum, int nb) {
  int t = threadIdx.x;
  int v = (t < nb) ? bsum[t] : 0;
  #pragma unroll
  for (int ofs = 1; ofs < 64; ofs <<= 1) {
    int u = __shfl_up(v, ofs);
    if (t >= ofs) v += u;
  }
  if (t < nb) bsum[t] = v;
}

// offs[i+1] = loc[i] + prefix(block); cur[i] = offs[i+1] - deg[i]
__global__ __launch_bounds__(1024) void k_offs(const int* __restrict__ loc,
                                               const int* __restrict__ bsum,
                                               const int* __restrict__ deg,
                                               int* __restrict__ offs,
                                               int* __restrict__ cur, int n) {
  int b = blockIdx.x;
  int i = b * 1024 + threadIdx.x;
  int base = (b > 0) ? bsum[b - 1] : 0;
  if (i < n) {
    int v = base + loc[i];
    offs[i + 1] = v;
    cur[i] = v - deg[i];
  }
  if (i == 0) offs[0] = 0;
}

__global__ void k_fill(const int* __restrict__ src, const int* __restrict__ dst,
                       int* __restrict__ cur, int* __restrict__ adj, int E) {
  int i = blockIdx.x * blockDim.x + threadIdx.x;
  if (i < E) {
    int p = atomicAdd(&cur[src[i]], 1);
    adj[p] = dst[i];
  }
}

// Pack W1 [8][128][64] into MFMA b-frag order
__global__ void k_packW1(const float* __restrict__ W1, u16* __restrict__ hi,
                         u16* __restrict__ lo) {
  int idx = blockIdx.x * 256 + threadIdx.x;
  if (idx >= 32 * 4 * 64 * 8) return;
  int j = idx & 7, lane = (idx >> 3) & 63, ks = (idx >> 9) & 3, cg = idx >> 11;
  int col = cg * 16 + (lane & 15);
  int k = ks * 32 + (lane >> 4) * 8 + j;
  float f = W1[((size_t)(col >> 6) * 128 + k) * 64 + (col & 63)];
  u16 h = f2bf(f);
  hi[idx] = h;
  lo[idx] = f2bf(f - bf2f(h));
}

// Pack W2 [8][512][8]
__global__ void k_packW2(const float* __restrict__ W2, u16* __restrict__ hi,
                         u16* __restrict__ lo) {
  int idx = blockIdx.x * 256 + threadIdx.x;
  if (idx >= 4 * 16 * 64 * 8) return;
  int j = idx & 7, lane = (idx >> 3) & 63, ks = (idx >> 9) & 15, cg = idx >> 13;
  int col = cg * 16 + (lane & 15);
  int k = ks * 32 + (lane >> 4) * 8 + j;
  float f = W2[((size_t)(col >> 3) * 512 + k) * 8 + (col & 7)];
  u16 h = f2bf(f);
  hi[idx] = h;
  lo[idx] = f2bf(f - bf2f(h));
}

// GEMM1: fp32 [N,128] x [128,512] -> bf16 [N,512] + fused per-(row,head) scores.
// Block: 64 rows x 512 cols; 4 waves, wave w covers cols w*128..+127 (heads 2w, 2w+1).
__global__ __launch_bounds__(256) void k_mgemm1(const float* __restrict__ x,
        const u16* __restrict__ bhi, const u16* __restrict__ blo,
        const float* __restrict__ a1, u16* __restrict__ H,
        float* __restrict__ ss, float* __restrict__ sdst, int N) {
  int w = threadIdx.x >> 6, lane = threadIdx.x & 63;
  int lr = lane & 15, lk = lane >> 4;
  int row0 = blockIdx.x * 64;
  int cg0 = w * 8;
  f32x4 acc[4][8] = {};
  for (int ks = 0; ks < 4; ++ks) {
    bf16x8 Ah[4], Al[4];
    #pragma unroll
    for (int rf = 0; rf < 4; ++rf) {
      int row = row0 + rf * 16 + lr;
      int rc = row < N ? row : 0;
      const float* ap = x + (size_t)rc * 128 + ks * 32 + lk * 8;
      float4 f0 = *reinterpret_cast<const float4*>(ap);
      float4 f1 = *reinterpret_cast<const float4*>(ap + 4);
      float fa[8] = {f0.x, f0.y, f0.z, f0.w, f1.x, f1.y, f1.z, f1.w};
      union { u32 u[4]; bf16x8 v; } ch, cl;
      #pragma unroll
      for (int p = 0; p < 4; ++p) {
        float e0 = fa[2 * p], e1 = fa[2 * p + 1];
        u32 h = cvt_pk_bf16(e0, e1);
        float r0 = e0 - bitsf(h << 16);
        float r1 = e1 - bitsf(h & 0xffff0000u);
        ch.u[p] = h;
        cl.u[p] = cvt_pk_bf16(r0, r1);
      }
      Ah[rf] = ch.v;
      Al[rf] = cl.v;
    }
    #pragma unroll
    for (int cf = 0; cf < 8; ++cf) {
      size_t bidx = ((size_t)((cg0 + cf) * 4 + ks) * 64 + lane) * 8;
      bf16x8 Bh = *reinterpret_cast<const bf16x8*>(&bhi[bidx]);
      bf16x8 Bl = *reinterpret_cast<const bf16x8*>(&blo[bidx]);
      #pragma unroll
      for (int rf = 0; rf < 4; ++rf) {
        acc[rf][cf] = __builtin_amdgcn_mfma_f32_16x16x32_bf16(Ah[rf], Bh, acc[rf][cf], 0, 0, 0);
        acc[rf][cf] = __builtin_amdgcn_mfma_f32_16x16x32_bf16(Al[rf], Bh, acc[rf][cf], 0, 0, 0);
        acc[rf][cf] = __builtin_amdgcn_mfma_f32_16x16x32_bf16(Ah[rf], Bl, acc[rf][cf], 0, 0, 0);
      }
    }
  }
  // epilogue: store bf16 H + fused scores
  float asr[8], adt[8];
  #pragma unroll
  for (int cf = 0; cf < 8; ++cf) {
    int h = 2 * w + (cf >> 2);
    int j = (cf & 3) * 16 + lr;
    asr[cf] = a1[h * 128 + j];
    adt[cf] = a1[h * 128 + 64 + j];
  }
  #pragma unroll
  for (int rf = 0; rf < 4; ++rf) {
    #pragma unroll
    for (int r = 0; r < 4; ++r) {
      int row = row0 + rf * 16 + lk * 4 + r;
      if (row < N) {
        #pragma unroll
        for (int cf = 0; cf < 8; ++cf)
          H[(size_t)row * 512 + cg0 * 16 + cf * 16 + lr] =
              (u16)cvt_pk_bf16(acc[rf][cf][r], acc[rf][cf][r]);
      }
      float p0s = 0.f, p0d = 0.f, p1s = 0.f, p1d = 0.f;
      #pragma unroll
      for (int cf = 0; cf < 4; ++cf) {
        p0s = fmaf(acc[rf][cf][r], asr[cf], p0s);
        p0d = fmaf(acc[rf][cf][r], adt[cf], p0d);
      }
      #pragma unroll
      for (int cf = 4; cf < 8; ++cf) {
        p1s = fmaf(acc[rf][cf][r], asr[cf], p1s);
        p1d = fmaf(acc[rf][cf][r], adt[cf], p1d);
      }
      #pragma unroll
      for (int m = 1; m < 16; m <<= 1) {
        p0s += __shfl_xor(p0s, m);
        p0d += __shfl_xor(p0d, m);
        p1s += __shfl_xor(p1s, m);
        p1d += __shfl_xor(p1d, m);
      }
      if (lr == 0 && row < N) {
        ss[row * 8 + 2 * w]       = p0s;
        sdst[row * 8 + 2 * w]     = p0d;
        ss[row * 8 + 2 * w + 1]   = p1s;
        sdst[row * 8 + 2 * w + 1] = p1d;
      }
    }
  }
}

// GEMM2: bf16 [N,512] x [512,64] -> bf16 [N,64] + fused scores.
__global__ __launch_bounds__(256) void k_mgemm2(const u16* __restrict__ A,
        const u16* __restrict__ bhi, const u16* __restrict__ blo,
        const float* __restrict__ a2, u16* __restrict__ H2,
        float* __restrict__ ss, float* __restrict__ sdst, int N) {
  int w = threadIdx.x >> 6, lane = threadIdx.x & 63;
  int lr = lane & 15, lk = lane >> 4;
  int row0 = blockIdx.x * 128 + w * 32;
  f32x4 acc[2][4] = {};
  for (int ks = 0; ks < 16; ++ks) {
    bf16x8 Ah[2];
    #pragma unroll
    for (int rf = 0; rf < 2; ++rf) {
      int row = row0 + rf * 16 + lr;
      int rc = row < N ? row : 0;
      size_t aidx = (size_t)rc * 512 + ks * 32 + lk * 8;
      Ah[rf] = *reinterpret_cast<const bf16x8*>(&A[aidx]);
    }
    #pragma unroll
    for (int cf = 0; cf < 4; ++cf) {
      size_t bidx = ((size_t)(cf * 16 + ks) * 64 + lane) * 8;
      bf16x8 Bh = *reinterpret_cast<const bf16x8*>(&bhi[bidx]);
      bf16x8 Bl = *reinterpret_cast<const bf16x8*>(&blo[bidx]);
      #pragma unroll
      for (int rf = 0; rf < 2; ++rf) {
        acc[rf][cf] = __builtin_amdgcn_mfma_f32_16x16x32_bf16(Ah[rf], Bh, acc[rf][cf], 0, 0, 0);
        acc[rf][cf] = __builtin_amdgcn_mfma_f32_16x16x32_bf16(Ah[rf], Bl, acc[rf][cf], 0, 0, 0);
      }
    }
  }
  int hh = lr >> 3, jj = lr & 7;
  float a2s[4], a2d[4];
  #pragma unroll
  for (int cf = 0; cf < 4; ++cf) {
    int h = cf * 2 + hh;
    a2s[cf] = a2[h * 16 + jj];
    a2d[cf] = a2[h * 16 + 8 + jj];
  }
  #pragma unroll
  for (int rf = 0; rf < 2; ++rf) {
    #pragma unroll
    for (int r = 0; r < 4; ++r) {
      int row = row0 + rf * 16 + lk * 4 + r;
      if (row < N) {
        #pragma unroll
        for (int cf = 0; cf < 4; ++cf)
          H2[(size_t)row * 64 + cf * 16 + lr] =
              (u16)cvt_pk_bf16(acc[rf][cf][r], acc[rf][cf][r]);
      }
      float ps[4], pd[4];
      #pragma unroll
      for (int cf = 0; cf < 4; ++cf) {
        ps[cf] = acc[rf][cf][r] * a2s[cf];
        pd[cf] = acc[rf][cf][r] * a2d[cf];
      }
      #pragma unroll
      for (int m = 1; m < 8; m <<= 1) {
        #pragma unroll
        for (int cf = 0; cf < 4; ++cf) {
          ps[cf] += __shfl_xor(ps[cf], m);
          pd[cf] += __shfl_xor(pd[cf], m);
        }
      }
      if (jj == 0 && row < N) {
        #pragma unroll
        for (int cf = 0; cf < 4; ++cf) {
          int h = cf * 2 + hh;
          ss[row * 8 + h]   = ps[cf];
          sdst[row * 8 + h] = pd[cf];
        }
      }
    }
  }
}

// unpack u32 (2 bf16) -> f32x2
__device__ inline f32x2 up2(u32 q) {
  f32x2 p;
  p.x = bitsf(q << 16);
  p.y = bitsf(q & 0xffff0000u);
  return p;
}

// Layer-1 aggregation: one wave per node. lane = (head = lane>>3, li = lane&7).
// Each lane computes ONE weight (edge li, its head); broadcast via shfl.
__global__ __launch_bounds__(256) void k_agg1(const u16* __restrict__ H,
        const float* __restrict__ ss, const float* __restrict__ sd,
        const int* __restrict__ offs, const int* __restrict__ adj,
        u16* __restrict__ o1, int n) {
  int node = (blockIdx.x * 256 + threadIdx.x) >> 6;
  int lane = threadIdx.x & 63;
  if (node >= n) return;
  int head = lane >> 3, li = lane & 7;
  int beg = offs[node], end = offs[node + 1];
  float sS = ss[node * 8 + head];
  f32x2 acc2[4] = {};
  float rsum = 0.f;
  int e = beg;
  for (; e + 8 <= end; e += 8) {
    int dl = adj[e + li];
    int dr[8];
    #pragma unroll
    for (int i = 0; i < 8; i++) dr[i] = __shfl(dl, i);
    uint4 rv[8];
    #pragma unroll
    for (int i = 0; i < 8; i++) rv[i] = ld16(H, (u32)dr[i] * 1024u + lane * 16u);
    float z = sS + sd[(u32)dl * 8u + head];
    float w = __expf(-(z > 0.f ? z : 0.2f * z));
    float wv[8];
    #pragma unroll
    for (int i = 0; i < 8; i++) wv[i] = __shfl(w, head * 8 + i);
    #pragma unroll
    for (int i = 0; i < 8; i++) {
      rsum += wv[i];
      f32x2 w2 = {wv[i], wv[i]};
      acc2[0] += w2 * up2(rv[i].x);
      acc2[1] += w2 * up2(rv[i].y);
      acc2[2] += w2 * up2(rv[i].z);
      acc2[3] += w2 * up2(rv[i].w);
    }
  }
  if (e < end) {
    int m = end - e;
    int lic = li < m ? li : m - 1;
    int dl = adj[e + lic];
    int dr[8];
    #pragma unroll
    for (int i = 0; i < 8; i++) dr[i] = __shfl(dl, i);
    uint4 rv[8];
    #pragma unroll
    for (int i = 0; i < 8; i++)
      if (i < m) rv[i] = ld16(H, (u32)dr[i] * 1024u + lane * 16u);
    float z = sS + sd[(u32)dl * 8u + head];
    float w = __expf(-(z > 0.f ? z : 0.2f * z));
    float wv[8];
    #pragma unroll
    for (int i = 0; i < 8; i++) wv[i] = __shfl(w, head * 8 + i);
    #pragma unroll
    for (int i = 0; i < 8; i++) {
      if (i < m) {
        rsum += wv[i];
        f32x2 w2 = {wv[i], wv[i]};
        acc2[0] += w2 * up2(rv[i].x);
        acc2[1] += w2 * up2(rv[i].y);
        acc2[2] += w2 * up2(rv[i].z);
        acc2[3] += w2 * up2(rv[i].w);
      }
    }
  }
  float inv = 1.f / rsum;
  float o[8];
  #pragma unroll
  for (int k = 0; k < 4; k++) {
    float v0 = acc2[k].x * inv, v1 = acc2[k].y * inv;
    o[2 * k]     = v0 > 0.f ? v0 : expm1f(v0);
    o[2 * k + 1] = v1 > 0.f ? v1 : expm1f(v1);
  }
  uint4 ph;
  ph.x = cvt_pk_bf16(o[0], o[1]);
  ph.y = cvt_pk_bf16(o[2], o[3]);
  ph.z = cvt_pk_bf16(o[4], o[5]);
  ph.w = cvt_pk_bf16(o[6], o[7]);
  reinterpret_cast<uint4*>(o1)[(size_t)node * 64 + lane] = ph;
}

// Layer-2 aggregation: one wave per node; lane = (li = lane>>3, fg = lane&7).
__global__ __launch_bounds__(256) void k_agg2(const u16* __restrict__ H,
        const float* __restrict__ ss, const float* __restrict__ sd,
        const int* __restrict__ offs, const int* __restrict__ adj,
        float* __restrict__ outp, int n) {
  int node = (blockIdx.x * 256 + threadIdx.x) >> 6;
  int lane = threadIdx.x & 63;
  if (node >= n) return;
  int li = lane >> 3, fg = lane & 7;
  int beg = offs[node], end = offs[node + 1];
  float sS = ss[node * 8 + fg];
  f32x2 acc2[4] = {};
  float rsum = 0.f;
  int e = beg;
  for (; e + 8 <= end; e += 8) {
    int dl = adj[e + (lane & 7)];
    u32 d = (u32)__shfl(dl, li);
    uint4 rv = ld16(H, d * 128u + fg * 16u);
    float z = sS + sd[d * 8u + fg];
    float w = __expf(-(z > 0.f ? z : 0.2f * z));
    rsum += w;
    f32x2 w2 = {w, w};
    acc2[0] += w2 * up2(rv.x);
    acc2[1] += w2 * up2(rv.y);
    acc2[2] += w2 * up2(rv.z);
    acc2[3] += w2 * up2(rv.w);
  }
  if (e < end) {
    int m = end - e;
    int ll = lane & 7; if (ll >= m) ll = m - 1;
    int dl = adj[e + ll];
    u32 d = (u32)__shfl(dl, li);
    if (li < m) {
      uint4 rv = ld16(H, d * 128u + fg * 16u);
      float z = sS + sd[d * 8u + fg];
      float w = __expf(-(z > 0.f ? z : 0.2f * z));
      rsum += w;
      f32x2 w2 = {w, w};
      acc2[0] += w2 * up2(rv.x);
      acc2[1] += w2 * up2(rv.y);
      acc2[2] += w2 * up2(rv.z);
      acc2[3] += w2 * up2(rv.w);
    }
  }
  #pragma unroll
  for (int mask = 8; mask < 64; mask <<= 1) {
    rsum += __shfl_xor(rsum, mask);
    #pragma unroll
    for (int k = 0; k < 4; k++) {
      acc2[k].x += __shfl_xor(acc2[k].x, mask);
      acc2[k].y += __shfl_xor(acc2[k].y, mask);
    }
  }
  if (li == 0) {
    float inv = 1.f / rsum;
    float o[8];
    #pragma unroll
    for (int k = 0; k < 4; k++) {
      float v0 = acc2[k].x * inv, v1 = acc2[k].y * inv;
      o[2 * k]     = v0 > 0.f ? v0 : expm1f(v0);
      o[2 * k + 1] = v1 > 0.f ? v1 : expm1f(v1);
    }
    float4* Ov = reinterpret_cast<float4*>(outp);
    Ov[(size_t)node * 16 + fg * 2]     = make_float4(o[0], o[1], o[2], o[3]);
    Ov[(size_t)node * 16 + fg * 2 + 1] = make_float4(o[4], o[5], o[6], o[7]);
  }
}

extern "C" void kernel_launch(void* const* d_in, const int* in_sizes, int n_in,
                              void* d_out, int out_size, void* d_ws, size_t ws_size,
                              hipStream_t stream) {
  const float* x  = (const float*)d_in[0];
  const int*   ei = (const int*)d_in[1];
  const float* W1 = (const float*)d_in[2];
  const float* a1 = (const float*)d_in[3];
  const float* W2 = (const float*)d_in[4];
  const float* a2 = (const float*)d_in[5];
  float* out = (float*)d_out;

  int N = in_sizes[0] / TNFEAT;   // 50000
  int E = in_sizes[1] / 2;        // 850000
  const int* src = ei;
  const int* dst = ei + E;
  int NB = (N + 1023) / 1024;     // scan blocks

  char* base = (char*)d_ws;
  size_t off = 0;
  auto take = [&](size_t bytes) { char* p = base + off; off = (off + bytes + 255) & ~(size_t)255; return p; };
  u16*   h_all = (u16*)take((size_t)N * C1 * 2);
  u16*   h1    = (u16*)take((size_t)N * C1 * 2);
  u16*   h2p   = (u16*)take((size_t)N * C2 * 2);
  u16*   w1hi  = (u16*)take(65536 * 2);
  u16*   w1lo  = (u16*)take(65536 * 2);
  u16*   w2hi  = (u16*)take(32768 * 2);
  u16*   w2lo  = (u16*)take(32768 * 2);
  float* s1s   = (float*)take((size_t)N * 8 * 4);
  float* s1d   = (float*)take((size_t)N * 8 * 4);
  float* s2s   = (float*)take((size_t)N * 8 * 4);
  float* s2d   = (float*)take((size_t)N * 8 * 4);
  int*   deg   = (int*)take((size_t)N * 4);
  int*   offs  = (int*)take((size_t)(N + 1) * 4);
  int*   cur   = (int*)take((size_t)N * 4);
  int*   loc   = (int*)take((size_t)N * 4);
  int*   bsum  = (int*)take(64 * 4);
  int*   adj   = (int*)take((size_t)E * 4);

  // CSR build (by src)
  hipLaunchKernelGGL(k_zero, dim3((N + 255) / 256), dim3(256), 0, stream, deg, N);
  hipLaunchKernelGGL(k_hist, dim3((E + 255) / 256), dim3(256), 0, stream, src, deg, E);
  hipLaunchKernelGGL(k_bscan1, dim3(NB), dim3(1024), 0, stream, deg, loc, bsum, N);
  hipLaunchKernelGGL(k_bscan2, dim3(1), dim3(64), 0, stream, bsum, NB);
  hipLaunchKernelGGL(k_offs, dim3(NB), dim3(1024), 0, stream, loc, bsum, deg, offs, cur, N);
  hipLaunchKernelGGL(k_fill, dim3((E + 255) / 256), dim3(256), 0, stream, src, dst, cur, adj, E);

  // Pack weights into fragment order
  hipLaunchKernelGGL(k_packW1, dim3(256), dim3(256), 0, stream, W1, w1hi, w1lo);
  hipLaunchKernelGGL(k_packW2, dim3(128), dim3(256), 0, stream, W2, w2hi, w2lo);

  // Layer 1 (GEMM + fused scores, then aggregation)
  hipLaunchKernelGGL(k_mgemm1, dim3((N + 63) / 64), dim3(256), 0, stream,
                     x, w1hi, w1lo, a1, h_all, s1s, s1d, N);
  hipLaunchKernelGGL(k_agg1, dim3((N + 3) / 4), dim3(256), 0, stream,
                     h_all, s1s, s1d, offs, adj, h1, N);

  // Layer 2
  hipLaunchKernelGGL(k_mgemm2, dim3((N + 127) / 128), dim3(256), 0, stream,
                     h1, w2hi, w2lo, a2, h2p, s2s, s2d, N);
  hipLaunchKernelGGL(k_agg2, dim3((N + 3) / 4), dim3(256), 0, stream,
                     h2p, s2s, s2d, offs, adj, out, N);
}

// Round 7
// 314.818 us; speedup vs baseline: 3.7850x; 1.1483x over previous
//
#include <hip/hip_runtime.h>
#include <math.h>

typedef unsigned int u32;
typedef unsigned short u16;
typedef __attribute__((ext_vector_type(8))) short bf16x8;
typedef __attribute__((ext_vector_type(4))) float f32x4;
typedef __attribute__((ext_vector_type(2))) float f32x2;

static constexpr int TNFEAT  = 128;
static constexpr int TNHEADS = 8;
static constexpr int C1      = 512;  // NHID*NHEADS
static constexpr int C2      = 64;   // NCLASS

__device__ inline float bf2f(u16 u) {
  union { u32 i; float f; } c; c.i = ((u32)u) << 16; return c.f;
}
__device__ inline float bitsf(u32 u) {
  union { u32 i; float f; } c; c.i = u; return c.f;
}
__device__ inline u16 f2bf(float f) {
  union { float f; u32 i; } c; c.f = f;
  u32 r = c.i + 0x7FFF + ((c.i >> 16) & 1);   // round-nearest-even
  return (u16)(r >> 16);
}
__device__ inline u32 cvt_pk_bf16(float lo, float hi) {
  u32 r;
  asm volatile("v_cvt_pk_bf16_f32 %0, %1, %2" : "=v"(r) : "v"(lo), "v"(hi));
  return r;
}
__device__ inline uint4 ld16(const u16* base, u32 byteoff) {
  return *reinterpret_cast<const uint4*>(reinterpret_cast<const char*>(base) + byteoff);
}
__device__ inline f32x2 up2(u32 q) {
  f32x2 p;
  p.x = bitsf(q << 16);
  p.y = bitsf(q & 0xffff0000u);
  return p;
}

__global__ void k_zero(int* __restrict__ p, int n) {
  int i = blockIdx.x * blockDim.x + threadIdx.x;
  if (i < n) p[i] = 0;
}

__global__ void k_hist(const int* __restrict__ src, int* __restrict__ deg, int E) {
  int i = blockIdx.x * blockDim.x + threadIdx.x;
  if (i < E) atomicAdd(&deg[src[i]], 1);
}

__global__ __launch_bounds__(1024) void k_bscan1(const int* __restrict__ deg,
                                                 int* __restrict__ loc,
                                                 int* __restrict__ bsum, int n) {
  __shared__ int sdata[1024];
  int t = threadIdx.x;
  int i = blockIdx.x * 1024 + t;
  int v = (i < n) ? deg[i] : 0;
  sdata[t] = v;
  __syncthreads();
  for (int ofs = 1; ofs < 1024; ofs <<= 1) {
    int tv = (t >= ofs) ? sdata[t - ofs] : 0;
    __syncthreads();
    sdata[t] += tv;
    __syncthreads();
  }
  if (i < n) loc[i] = sdata[t];
  if (t == 1023) bsum[blockIdx.x] = sdata[1023];
}

__global__ void k_bscan2(int* __restrict__ bsum, int nb) {
  int t = threadIdx.x;
  int v = (t < nb) ? bsum[t] : 0;
  #pragma unroll
  for (int ofs = 1; ofs < 64; ofs <<= 1) {
    int u = __shfl_up(v, ofs);
    if (t >= ofs) v += u;
  }
  if (t < nb) bsum[t] = v;
}

__global__ __launch_bounds__(1024) void k_offs(const int* __restrict__ loc,
                                               const int* __restrict__ bsum,
                                               const int* __restrict__ deg,
                                               int* __restrict__ offs,
                                               int* __restrict__ cur, int n) {
  int b = blockIdx.x;
  int i = b * 1024 + threadIdx.x;
  int base = (b > 0) ? bsum[b - 1] : 0;
  if (i < n) {
    int v = base + loc[i];
    offs[i + 1] = v;
    cur[i] = v - deg[i];
  }
  if (i == 0) offs[0] = 0;
}

__global__ void k_fill(const int* __restrict__ src, const int* __restrict__ dst,
                       int* __restrict__ cur, int* __restrict__ adj, int E) {
  int i = blockIdx.x * blockDim.x + threadIdx.x;
  if (i < E) {
    int p = atomicAdd(&cur[src[i]], 1);
    adj[p] = dst[i];
  }
}

// Pack W1 [8][128][64] into MFMA b-frag order (shared by mgemm1c: cg = head*4+cf)
__global__ void k_packW1(const float* __restrict__ W1, u16* __restrict__ hi,
                         u16* __restrict__ lo) {
  int idx = blockIdx.x * 256 + threadIdx.x;
  if (idx >= 32 * 4 * 64 * 8) return;
  int j = idx & 7, lane = (idx >> 3) & 63, ks = (idx >> 9) & 3, cg = idx >> 11;
  int col = cg * 16 + (lane & 15);
  int k = ks * 32 + (lane >> 4) * 8 + j;
  float f = W1[((size_t)(col >> 6) * 128 + k) * 64 + (col & 63)];
  u16 h = f2bf(f);
  hi[idx] = h;
  lo[idx] = f2bf(f - bf2f(h));
}

// Pack W2 [8][512][8]
__global__ void k_packW2(const float* __restrict__ W2, u16* __restrict__ hi,
                         u16* __restrict__ lo) {
  int idx = blockIdx.x * 256 + threadIdx.x;
  if (idx >= 4 * 16 * 64 * 8) return;
  int j = idx & 7, lane = (idx >> 3) & 63, ks = (idx >> 9) & 15, cg = idx >> 13;
  int col = cg * 16 + (lane & 15);
  int k = ks * 32 + (lane >> 4) * 8 + j;
  float f = W2[((size_t)(col >> 3) * 512 + k) * 8 + (col & 7)];
  u16 h = f2bf(f);
  hi[idx] = h;
  lo[idx] = f2bf(f - bf2f(h));
}

// Vsd[k][c] = sum_f W1[h][k][f] * a1[h][s*64+f], c = h*2+s; packed in b-frag order.
__global__ void k_packVsd(const float* __restrict__ W1, const float* __restrict__ a1,
                          u16* __restrict__ vhi, u16* __restrict__ vlo) {
  int idx = blockIdx.x * 256 + threadIdx.x;   // 2048 total
  if (idx >= 2048) return;
  int j = idx & 7, lane = (idx >> 3) & 63, ks = idx >> 9;
  int k = ks * 32 + (lane >> 4) * 8 + j;
  int c = lane & 15;
  int h = c >> 1, s = c & 1;
  const float* wrow = W1 + ((size_t)h * 128 + k) * 64;
  const float* av = a1 + h * 128 + s * 64;
  float dot = 0.f;
  #pragma unroll 8
  for (int f = 0; f < 64; f++) dot = fmaf(wrow[f], av[f], dot);
  u16 hb = f2bf(dot);
  vhi[idx] = hb;
  vlo[idx] = f2bf(dot - bf2f(hb));
}

// x [N,128] fp32 -> xb bf16 [N,128]; scores [N,16] = x @ Vsd -> s1s/s1d (3-term MFMA)
__global__ __launch_bounds__(256) void k_xprep(const float* __restrict__ x,
        const u16* __restrict__ vhi, const u16* __restrict__ vlo,
        u16* __restrict__ xb, float* __restrict__ ss, float* __restrict__ sd, int N) {
  int w = threadIdx.x >> 6, lane = threadIdx.x & 63;
  int lr = lane & 15, lk = lane >> 4;
  int row0 = blockIdx.x * 64 + w * 16;
  f32x4 acc = {0.f, 0.f, 0.f, 0.f};
  for (int ks = 0; ks < 4; ++ks) {
    int row = row0 + lr;
    int rc = row < N ? row : 0;
    const float* ap = x + (size_t)rc * 128 + ks * 32 + lk * 8;
    float4 f0 = *reinterpret_cast<const float4*>(ap);
    float4 f1 = *reinterpret_cast<const float4*>(ap + 4);
    float fa[8] = {f0.x, f0.y, f0.z, f0.w, f1.x, f1.y, f1.z, f1.w};
    union { u32 u[4]; bf16x8 v; uint4 q; } ch, cl;
    #pragma unroll
    for (int p = 0; p < 4; ++p) {
      float e0 = fa[2 * p], e1 = fa[2 * p + 1];
      u32 h = cvt_pk_bf16(e0, e1);
      ch.u[p] = h;
      cl.u[p] = cvt_pk_bf16(e0 - bitsf(h << 16), e1 - bitsf(h & 0xffff0000u));
    }
    if (row < N)
      *reinterpret_cast<uint4*>(&xb[(size_t)row * 128 + ks * 32 + lk * 8]) = ch.q;
    size_t bidx = ((size_t)ks * 64 + lane) * 8;
    bf16x8 Bh = *reinterpret_cast<const bf16x8*>(&vhi[bidx]);
    bf16x8 Bl = *reinterpret_cast<const bf16x8*>(&vlo[bidx]);
    acc = __builtin_amdgcn_mfma_f32_16x16x32_bf16(ch.v, Bh, acc, 0, 0, 0);
    acc = __builtin_amdgcn_mfma_f32_16x16x32_bf16(cl.v, Bh, acc, 0, 0, 0);
    acc = __builtin_amdgcn_mfma_f32_16x16x32_bf16(ch.v, Bl, acc, 0, 0, 0);
  }
  int h = lr >> 1, s = lr & 1;
  float* dstp = (s == 0) ? ss : sd;
  #pragma unroll
  for (int r = 0; r < 4; ++r) {
    int row = row0 + lk * 4 + r;
    if (row < N) dstp[row * 8 + h] = acc[r];
  }
}

// Layer-1 x-aggregation: one wave per node. Weight lanes: (head=lane>>3, li=lane&7);
// accumulation lanes: lane = feat-pair (feats 2l, 2l+1), 8 heads per lane.
// g[node][head][128] bf16 weighted x-sums + rsum[node][head].
__global__ __launch_bounds__(256) void k_agg1x(const u16* __restrict__ xb,
        const float* __restrict__ ss, const float* __restrict__ sd,
        const int* __restrict__ offs, const int* __restrict__ adj,
        u16* __restrict__ g, float* __restrict__ rs, int n) {
  int node = (blockIdx.x * 256 + threadIdx.x) >> 6;
  int lane = threadIdx.x & 63;
  if (node >= n) return;
  int head = lane >> 3, li = lane & 7;
  int beg = offs[node], end = offs[node + 1];
  float sS = ss[node * 8 + head];
  f32x2 acc2[8] = {};
  float rsum = 0.f;
  int e = beg;
  for (; e + 8 <= end; e += 8) {
    int dl = adj[e + li];
    float z = sS + sd[(u32)dl * 8u + head];
    float w = __expf(-(z > 0.f ? z : 0.2f * z));
    rsum += w;
    int dr[8];
    #pragma unroll
    for (int i = 0; i < 8; i++) dr[i] = __shfl(dl, i);
    u32 qv[8];
    #pragma unroll
    for (int i = 0; i < 8; i++)
      qv[i] = *reinterpret_cast<const u32*>(
          reinterpret_cast<const char*>(xb) + (u32)dr[i] * 256u + lane * 4u);
    #pragma unroll
    for (int i = 0; i < 8; i++) {
      f32x2 xv = up2(qv[i]);
      #pragma unroll
      for (int h2 = 0; h2 < 8; h2++) {
        float wi = __shfl(w, h2 * 8 + i);
        acc2[h2] += (f32x2){wi, wi} * xv;
      }
    }
  }
  if (e < end) {
    int m = end - e;
    int lic = li < m ? li : m - 1;
    int dl = adj[e + lic];
    float z = sS + sd[(u32)dl * 8u + head];
    float w = __expf(-(z > 0.f ? z : 0.2f * z));
    if (li >= m) w = 0.f;
    rsum += w;
    int dr[8];
    #pragma unroll
    for (int i = 0; i < 8; i++) dr[i] = __shfl(dl, i);
    u32 qv[8];
    #pragma unroll
    for (int i = 0; i < 8; i++)
      if (i < m)
        qv[i] = *reinterpret_cast<const u32*>(
            reinterpret_cast<const char*>(xb) + (u32)dr[i] * 256u + lane * 4u);
    #pragma unroll
    for (int i = 0; i < 8; i++) {
      if (i < m) {
        f32x2 xv = up2(qv[i]);
        #pragma unroll
        for (int h2 = 0; h2 < 8; h2++) {
          float wi = __shfl(w, h2 * 8 + i);
          acc2[h2] += (f32x2){wi, wi} * xv;
        }
      }
    }
  }
  // rsum: reduce over li within each head group
  rsum += __shfl_xor(rsum, 1);
  rsum += __shfl_xor(rsum, 2);
  rsum += __shfl_xor(rsum, 4);
  if (li == 0) rs[node * 8 + head] = rsum;
  // g write: lane l holds feats (2l, 2l+1) for all heads
  u32* gu = reinterpret_cast<u32*>(g);
  #pragma unroll
  for (int h2 = 0; h2 < 8; h2++)
    gu[((size_t)node * 8 + h2) * 64 + lane] = cvt_pk_bf16(acc2[h2].x, acc2[h2].y);
}

// Per-head GEMM: h1[row][head*64+c] = elu((g[row][head] @ W1[head])[c] / rsum)
__global__ __launch_bounds__(256) void k_mgemm1c(const u16* __restrict__ g,
        const u16* __restrict__ bhi, const u16* __restrict__ blo,
        const float* __restrict__ rs, u16* __restrict__ h1, int N) {
  int w = threadIdx.x >> 6, lane = threadIdx.x & 63;
  int lr = lane & 15, lk = lane >> 4;
  int head = blockIdx.y;
  int row0 = blockIdx.x * 64 + w * 16;
  f32x4 acc[4] = {};
  for (int ks = 0; ks < 4; ++ks) {
    int row = row0 + lr;
    int rc = row < N ? row : 0;
    bf16x8 Ah = *reinterpret_cast<const bf16x8*>(
        &g[((size_t)rc * 8 + head) * 128 + ks * 32 + lk * 8]);
    #pragma unroll
    for (int cf = 0; cf < 4; ++cf) {
      size_t bidx = ((size_t)((head * 4 + cf) * 4 + ks) * 64 + lane) * 8;
      bf16x8 Bh = *reinterpret_cast<const bf16x8*>(&bhi[bidx]);
      bf16x8 Bl = *reinterpret_cast<const bf16x8*>(&blo[bidx]);
      acc[cf] = __builtin_amdgcn_mfma_f32_16x16x32_bf16(Ah, Bh, acc[cf], 0, 0, 0);
      acc[cf] = __builtin_amdgcn_mfma_f32_16x16x32_bf16(Ah, Bl, acc[cf], 0, 0, 0);
    }
  }
  #pragma unroll
  for (int r = 0; r < 4; ++r) {
    int row = row0 + lk * 4 + r;
    if (row < N) {
      float inv = 1.f / rs[row * 8 + head];
      #pragma unroll
      for (int cf = 0; cf < 4; ++cf) {
        float v = acc[cf][r] * inv;
        v = v > 0.f ? v : expm1f(v);
        h1[(size_t)row * 512 + head * 64 + cf * 16 + lr] = (u16)cvt_pk_bf16(v, v);
      }
    }
  }
}

// GEMM2: bf16 [N,512] x [512,64] -> bf16 [N,64] + fused scores.
__global__ __launch_bounds__(256) void k_mgemm2(const u16* __restrict__ A,
        const u16* __restrict__ bhi, const u16* __restrict__ blo,
        const float* __restrict__ a2, u16* __restrict__ H2,
        float* __restrict__ ss, float* __restrict__ sdst, int N) {
  int w = threadIdx.x >> 6, lane = threadIdx.x & 63;
  int lr = lane & 15, lk = lane >> 4;
  int row0 = blockIdx.x * 128 + w * 32;
  f32x4 acc[2][4] = {};
  for (int ks = 0; ks < 16; ++ks) {
    bf16x8 Ah[2];
    #pragma unroll
    for (int rf = 0; rf < 2; ++rf) {
      int row = row0 + rf * 16 + lr;
      int rc = row < N ? row : 0;
      size_t aidx = (size_t)rc * 512 + ks * 32 + lk * 8;
      Ah[rf] = *reinterpret_cast<const bf16x8*>(&A[aidx]);
    }
    #pragma unroll
    for (int cf = 0; cf < 4; ++cf) {
      size_t bidx = ((size_t)(cf * 16 + ks) * 64 + lane) * 8;
      bf16x8 Bh = *reinterpret_cast<const bf16x8*>(&bhi[bidx]);
      bf16x8 Bl = *reinterpret_cast<const bf16x8*>(&blo[bidx]);
      #pragma unroll
      for (int rf = 0; rf < 2; ++rf) {
        acc[rf][cf] = __builtin_amdgcn_mfma_f32_16x16x32_bf16(Ah[rf], Bh, acc[rf][cf], 0, 0, 0);
        acc[rf][cf] = __builtin_amdgcn_mfma_f32_16x16x32_bf16(Ah[rf], Bl, acc[rf][cf], 0, 0, 0);
      }
    }
  }
  int hh = lr >> 3, jj = lr & 7;
  float a2s[4], a2d[4];
  #pragma unroll
  for (int cf = 0; cf < 4; ++cf) {
    int h = cf * 2 + hh;
    a2s[cf] = a2[h * 16 + jj];
    a2d[cf] = a2[h * 16 + 8 + jj];
  }
  #pragma unroll
  for (int rf = 0; rf < 2; ++rf) {
    #pragma unroll
    for (int r = 0; r < 4; ++r) {
      int row = row0 + rf * 16 + lk * 4 + r;
      if (row < N) {
        #pragma unroll
        for (int cf = 0; cf < 4; ++cf)
          H2[(size_t)row * 64 + cf * 16 + lr] =
              (u16)cvt_pk_bf16(acc[rf][cf][r], acc[rf][cf][r]);
      }
      float ps[4], pd[4];
      #pragma unroll
      for (int cf = 0; cf < 4; ++cf) {
        ps[cf] = acc[rf][cf][r] * a2s[cf];
        pd[cf] = acc[rf][cf][r] * a2d[cf];
      }
      #pragma unroll
      for (int m = 1; m < 8; m <<= 1) {
        #pragma unroll
        for (int cf = 0; cf < 4; ++cf) {
          ps[cf] += __shfl_xor(ps[cf], m);
          pd[cf] += __shfl_xor(pd[cf], m);
        }
      }
      if (jj == 0 && row < N) {
        #pragma unroll
        for (int cf = 0; cf < 4; ++cf) {
          int h = cf * 2 + hh;
          ss[row * 8 + h]   = ps[cf];
          sdst[row * 8 + h] = pd[cf];
        }
      }
    }
  }
}

// Layer-2 aggregation: one wave per node; lane = (li = lane>>3, fg = lane&7).
__global__ __launch_bounds__(256) void k_agg2(const u16* __restrict__ H,
        const float* __restrict__ ss, const float* __restrict__ sd,
        const int* __restrict__ offs, const int* __restrict__ adj,
        float* __restrict__ outp, int n) {
  int node = (blockIdx.x * 256 + threadIdx.x) >> 6;
  int lane = threadIdx.x & 63;
  if (node >= n) return;
  int li = lane >> 3, fg = lane & 7;
  int beg = offs[node], end = offs[node + 1];
  float sS = ss[node * 8 + fg];
  f32x2 acc2[4] = {};
  float rsum = 0.f;
  int e = beg;
  for (; e + 8 <= end; e += 8) {
    int dl = adj[e + (lane & 7)];
    u32 d = (u32)__shfl(dl, li);
    uint4 rv = ld16(H, d * 128u + fg * 16u);
    float z = sS + sd[d * 8u + fg];
    float w = __expf(-(z > 0.f ? z : 0.2f * z));
    rsum += w;
    f32x2 w2 = {w, w};
    acc2[0] += w2 * up2(rv.x);
    acc2[1] += w2 * up2(rv.y);
    acc2[2] += w2 * up2(rv.z);
    acc2[3] += w2 * up2(rv.w);
  }
  if (e < end) {
    int m = end - e;
    int ll = lane & 7; if (ll >= m) ll = m - 1;
    int dl = adj[e + ll];
    u32 d = (u32)__shfl(dl, li);
    if (li < m) {
      uint4 rv = ld16(H, d * 128u + fg * 16u);
      float z = sS + sd[d * 8u + fg];
      float w = __expf(-(z > 0.f ? z : 0.2f * z));
      rsum += w;
      f32x2 w2 = {w, w};
      acc2[0] += w2 * up2(rv.x);
      acc2[1] += w2 * up2(rv.y);
      acc2[2] += w2 * up2(rv.z);
      acc2[3] += w2 * up2(rv.w);
    }
  }
  #pragma unroll
  for (int mask = 8; mask < 64; mask <<= 1) {
    rsum += __shfl_xor(rsum, mask);
    #pragma unroll
    for (int k = 0; k < 4; k++) {
      acc2[k].x += __shfl_xor(acc2[k].x, mask);
      acc2[k].y += __shfl_xor(acc2[k].y, mask);
    }
  }
  if (li == 0) {
    float inv = 1.f / rsum;
    float o[8];
    #pragma unroll
    for (int k = 0; k < 4; k++) {
      float v0 = acc2[k].x * inv, v1 = acc2[k].y * inv;
      o[2 * k]     = v0 > 0.f ? v0 : expm1f(v0);
      o[2 * k + 1] = v1 > 0.f ? v1 : expm1f(v1);
    }
    float4* Ov = reinterpret_cast<float4*>(outp);
    Ov[(size_t)node * 16 + fg * 2]     = make_float4(o[0], o[1], o[2], o[3]);
    Ov[(size_t)node * 16 + fg * 2 + 1] = make_float4(o[4], o[5], o[6], o[7]);
  }
}

extern "C" void kernel_launch(void* const* d_in, const int* in_sizes, int n_in,
                              void* d_out, int out_size, void* d_ws, size_t ws_size,
                              hipStream_t stream) {
  const float* x  = (const float*)d_in[0];
  const int*   ei = (const int*)d_in[1];
  const float* W1 = (const float*)d_in[2];
  const float* a1 = (const float*)d_in[3];
  const float* W2 = (const float*)d_in[4];
  const float* a2 = (const float*)d_in[5];
  float* out = (float*)d_out;

  int N = in_sizes[0] / TNFEAT;   // 50000
  int E = in_sizes[1] / 2;        // 850000
  const int* src = ei;
  const int* dst = ei + E;
  int NB = (N + 1023) / 1024;

  char* base = (char*)d_ws;
  size_t off = 0;
  auto take = [&](size_t bytes) { char* p = base + off; off = (off + bytes + 255) & ~(size_t)255; return p; };
  u16*   xb    = (u16*)take((size_t)N * TNFEAT * 2);       // 12.8 MB
  u16*   g     = (u16*)take((size_t)N * 8 * TNFEAT * 2);   // 102.4 MB
  u16*   h1    = (u16*)take((size_t)N * C1 * 2);           // 51.2 MB
  u16*   h2p   = (u16*)take((size_t)N * C2 * 2);           // 6.4 MB
  u16*   w1hi  = (u16*)take(65536 * 2);
  u16*   w1lo  = (u16*)take(65536 * 2);
  u16*   w2hi  = (u16*)take(32768 * 2);
  u16*   w2lo  = (u16*)take(32768 * 2);
  u16*   vhi   = (u16*)take(2048 * 2);
  u16*   vlo   = (u16*)take(2048 * 2);
  float* s1s   = (float*)take((size_t)N * 8 * 4);
  float* s1d   = (float*)take((size_t)N * 8 * 4);
  float* s2s   = (float*)take((size_t)N * 8 * 4);
  float* s2d   = (float*)take((size_t)N * 8 * 4);
  float* rs    = (float*)take((size_t)N * 8 * 4);
  int*   deg   = (int*)take((size_t)N * 4);
  int*   offs  = (int*)take((size_t)(N + 1) * 4);
  int*   cur   = (int*)take((size_t)N * 4);
  int*   loc   = (int*)take((size_t)N * 4);
  int*   bsum  = (int*)take(64 * 4);
  int*   adj   = (int*)take((size_t)E * 4);

  // CSR build (by src)
  hipLaunchKernelGGL(k_zero, dim3((N + 255) / 256), dim3(256), 0, stream, deg, N);
  hipLaunchKernelGGL(k_hist, dim3((E + 255) / 256), dim3(256), 0, stream, src, deg, E);
  hipLaunchKernelGGL(k_bscan1, dim3(NB), dim3(1024), 0, stream, deg, loc, bsum, N);
  hipLaunchKernelGGL(k_bscan2, dim3(1), dim3(64), 0, stream, bsum, NB);
  hipLaunchKernelGGL(k_offs, dim3(NB), dim3(1024), 0, stream, loc, bsum, deg, offs, cur, N);
  hipLaunchKernelGGL(k_fill, dim3((E + 255) / 256), dim3(256), 0, stream, src, dst, cur, adj, E);

  // Weight packing + score-projection vectors
  hipLaunchKernelGGL(k_packW1, dim3(256), dim3(256), 0, stream, W1, w1hi, w1lo);
  hipLaunchKernelGGL(k_packW2, dim3(128), dim3(256), 0, stream, W2, w2hi, w2lo);
  hipLaunchKernelGGL(k_packVsd, dim3(8), dim3(256), 0, stream, W1, a1, vhi, vlo);

  // Layer 1: xb + scores, x-space aggregation, per-head GEMM (rsum/elu fused)
  hipLaunchKernelGGL(k_xprep, dim3((N + 63) / 64), dim3(256), 0, stream,
                     x, vhi, vlo, xb, s1s, s1d, N);
  hipLaunchKernelGGL(k_agg1x, dim3((N + 3) / 4), dim3(256), 0, stream,
                     xb, s1s, s1d, offs, adj, g, rs, N);
  hipLaunchKernelGGL(k_mgemm1c, dim3((N + 63) / 64, 8), dim3(256), 0, stream,
                     g, w1hi, w1lo, rs, h1, N);

  // Layer 2
  hipLaunchKernelGGL(k_mgemm2, dim3((N + 127) / 128), dim3(256), 0, stream,
                     h1, w2hi, w2lo, a2, h2p, s2s, s2d, N);
  hipLaunchKernelGGL(k_agg2, dim3((N + 3) / 4), dim3(256), 0, stream,
                     h2p, s2s, s2d, offs, adj, out, N);
}